// Round 6
// baseline (206.580 us; speedup 1.0000x reference)
//
#include <hip/hip_runtime.h>

typedef unsigned short u16;
typedef __fp16 halfx2 __attribute__((ext_vector_type(2)));
typedef __fp16 halfx8 __attribute__((ext_vector_type(8)));
typedef float floatx4 __attribute__((ext_vector_type(4)));
typedef unsigned short u16x4 __attribute__((ext_vector_type(4)));
typedef unsigned short u16x8 __attribute__((ext_vector_type(8)));

#define D_MODEL 768
#define NH 12
#define DH 64
#define SEQ 2048
#define BATCH 2
#define MTOK 4096            // BATCH*SEQ
#define DQKV 2304

__device__ __forceinline__ u16 f2h(float f) {
    __fp16 h = (__fp16)f;
    return __builtin_bit_cast(u16, h);
}

__device__ __forceinline__ void gload_lds16(const void* g, void* l) {
    __builtin_amdgcn_global_load_lds(
        (const __attribute__((address_space(1))) void*)g,
        (__attribute__((address_space(3))) void*)l, 16, 0, 0);
}

// ---------------- prep: W transposes -> f16 [n][k] (576 blocks) + x -> f16 cast (1536 blocks) ----------------

__global__ __launch_bounds__(256) void wprep_kernel(const float* __restrict__ Wq, const float* __restrict__ Wk,
                                                    const float* __restrict__ Wv, const float* __restrict__ Wo,
                                                    const float* __restrict__ x,
                                                    u16* __restrict__ WqkvT, u16* __restrict__ WoT,
                                                    u16* __restrict__ xh) {
    __shared__ u16 t[64][72];
    int bid = blockIdx.x;
    int tid = threadIdx.x;
    if (bid >= 576) {
        // x fp32 -> f16, 2048 elems per block
        int idx = (bid - 576) * 2048 + tid * 8;
        float4 v0 = *(const float4*)(x + idx);
        float4 v1 = *(const float4*)(x + idx + 4);
        union { u16x8 u; halfx2 h[4]; } pk;
        pk.h[0] = __builtin_amdgcn_cvt_pkrtz(v0.x, v0.y);
        pk.h[1] = __builtin_amdgcn_cvt_pkrtz(v0.z, v0.w);
        pk.h[2] = __builtin_amdgcn_cvt_pkrtz(v1.x, v1.y);
        pk.h[3] = __builtin_amdgcn_cvt_pkrtz(v1.z, v1.w);
        *(u16x8*)(xh + idx) = pk.u;
        return;
    }
    int z = bid / 144;
    int t2 = bid % 144;
    int k0 = (t2 / 12) * 64, n0 = (t2 % 12) * 64;
    const float* W = (z == 0) ? Wq : (z == 1) ? Wk : (z == 2) ? Wv : Wo;
    u16* dst = (z < 3) ? (WqkvT + (size_t)z * 768 * 768) : WoT;
#pragma unroll
    for (int p = 0; p < 16; ++p) {
        int idx = p * 256 + tid;
        int kr = idx >> 6, nc = idx & 63;
        t[kr][nc] = f2h(W[(size_t)(k0 + kr) * 768 + n0 + nc]);
    }
    __syncthreads();
#pragma unroll
    for (int p = 0; p < 16; ++p) {
        int idx = p * 256 + tid;
        int nr = idx >> 6, kc = idx & 63;
        dst[(size_t)(n0 + nr) * 768 + k0 + kc] = t[kc][nr];
    }
}

// ---------------- QKV GEMM, A staged from pre-cast f16 xh via global_load_lds ----------------
// 64x128 tile (1152 blocks), BK=64. Epilogue: Q -> qP[bh][s][64] pre-scaled by
// 0.125*log2e, K -> kP[bh][s][64], V -> vT[bh][d][s].

__global__ __launch_bounds__(256) void gemm_qkv(const u16* __restrict__ xh, const u16* __restrict__ Bt,
                                                const float* __restrict__ bq, const float* __restrict__ bk,
                                                const float* __restrict__ bv,
                                                u16* __restrict__ qP, u16* __restrict__ kP,
                                                u16* __restrict__ vTout) {
    const int tid = threadIdx.x;
    const int wid = tid >> 6;
    const int lane = tid & 63;
    const int qd = lane >> 4;
    const int l15 = lane & 15;

    const int tn = blockIdx.x * 128;   // 18 n-tiles
    const int tm = blockIdx.y * 64;    // 64 m-tiles
    const int wm = (wid >> 1) * 32;
    const int wn = (wid & 1) * 64;

    __shared__ alignas(16) u16 As[64 * 64];    // 8 KB
    __shared__ alignas(16) u16 Bs[128 * 64];   // 16 KB

    floatx4 acc[2][4];
#pragma unroll
    for (int i = 0; i < 2; ++i)
#pragma unroll
        for (int j = 0; j < 4; ++j) acc[i][j] = (floatx4)(0.0f);

    const u16* Ag[2];
#pragma unroll
    for (int rd = 0; rd < 2; ++rd) {
        int s = rd * 256 + tid;
        int r = s >> 3, bl = (s & 7) ^ (r & 7);
        Ag[rd] = xh + (size_t)(tm + r) * 768 + bl * 8;
    }
    const u16* Bg[4];
#pragma unroll
    for (int rd = 0; rd < 4; ++rd) {
        int s = rd * 256 + tid;
        int r = s >> 3, bl = (s & 7) ^ (r & 7);
        Bg[rd] = Bt + (size_t)(tn + r) * 768 + bl * 8;
    }

    for (int kb = 0; kb < 768; kb += 64) {
        __syncthreads();
#pragma unroll
        for (int rd = 0; rd < 2; ++rd)
            gload_lds16(Ag[rd] + kb, As + (size_t)(rd * 256 + tid) * 8);
#pragma unroll
        for (int rd = 0; rd < 4; ++rd)
            gload_lds16(Bg[rd] + kb, Bs + (size_t)(rd * 256 + tid) * 8);
        __syncthreads();

#pragma unroll
        for (int ks = 0; ks < 2; ++ks) {
            halfx8 af[2], bf[4];
#pragma unroll
            for (int i = 0; i < 2; ++i) {
                int r = wm + i * 16 + l15;
                af[i] = *(const halfx8*)(As + r * 64 + (((ks * 4 + qd) ^ (r & 7)) * 8));
            }
#pragma unroll
            for (int j = 0; j < 4; ++j) {
                int r2 = wn + j * 16 + l15;
                bf[j] = *(const halfx8*)(Bs + r2 * 64 + (((ks * 4 + qd) ^ (r2 & 7)) * 8));
            }
#pragma unroll
            for (int i = 0; i < 2; ++i)
#pragma unroll
                for (int j = 0; j < 4; ++j)
                    acc[i][j] = __builtin_amdgcn_mfma_f32_16x16x32_f16(af[i], bf[j], acc[i][j], 0, 0, 0);
        }
    }

    const float cscale = 0.125f * 1.44269504088896340736f;
    const int rgn = (tn < 768) ? 0 : (tn < 1536) ? 1 : 2;   // block-uniform
    const float* bsrc = (rgn == 0) ? bq : (rgn == 1) ? bk : bv;
#pragma unroll
    for (int j = 0; j < 4; ++j) {
        int col = tn + wn + j * 16 + l15;
        int cl = col - rgn * 768;
        float bvv = bsrc[cl];
        int h = cl >> 6, d = cl & 63;
#pragma unroll
        for (int i = 0; i < 2; ++i) {
            int row0 = tm + wm + i * 16 + qd * 4;
            int b = row0 >> 11, s0 = row0 & 2047;
            u16x4 pk;
#pragma unroll
            for (int r = 0; r < 4; ++r) {
                float v = acc[i][j][r] + bvv;
                if (rgn == 0) v *= cscale;
                pk[r] = f2h(v);
            }
            if (rgn == 2) {
                *(u16x4*)(vTout + ((size_t)(b * NH + h) * 64 + d) * SEQ + s0) = pk;
            } else {
                u16* dst = (rgn == 0) ? qP : kP;
#pragma unroll
                for (int r = 0; r < 4; ++r)
                    dst[((size_t)(b * NH + h) * SEQ + s0 + r) * DH + d] = pk[r];
            }
        }
    }
}

// ---------------- attention R17: R13 base + full-slack software pipeline ----------------
// grid = (24 bh, 32 q-tiles of 64), 4 waves, private 32-key strips, NO barrier
// in the loop. Every dependence gets >= 1 full iteration of slack:
//   K at distance 2 (kA/kB ping-pong): K(t+2) issued iter t, used QK(t+1) at t+1.
//   P double-buffered per wave: iter t = exp(t)->bufW, QK(t+1), READ bufR=P(t-1),
//     PV(t-1). The P write->read lgkm chain hides behind QK's 16 MFMA.
//   V at distance 1 (vA/vB): V(t) loaded iter t, consumed iter t+1's PV(t).
// Scalar-VALU lsum (saves 4 MFMA + 16 AGPR). ~230 unified regs < 256 at
// launch_bounds(256,2) -> no spills. LDS 36 KB (4 waves x 2 bufs x [64][36]),
// per-wave private (same conflict-free layout as R13).

__global__ __launch_bounds__(256, 2) void attn_kernel(const u16* __restrict__ qP, const u16* __restrict__ kP,
                                                      const u16* __restrict__ vT, u16* __restrict__ attn) {
    const int tid = threadIdx.x;
    const int wid = tid >> 6;
    const int lane = tid & 63;
    const int qd = lane >> 4;
    const int l15 = lane & 15;

    const int bh = blockIdx.x;
    const int b = bh / NH, h = bh % NH;
    const int q0 = blockIdx.y * 64;

    __shared__ alignas(16) u16 smem[18432];   // 36 KB: per wave 2 x [64][36] P bufs
    u16* ps0 = smem + wid * 4608;
    u16* ps1 = ps0 + 2304;

    halfx8 aq[4][2];
#pragma unroll
    for (int jn = 0; jn < 4; ++jn)
#pragma unroll
        for (int ks = 0; ks < 2; ++ks)
            aq[jn][ks] = *(const halfx8*)(qP + (size_t)(bh * SEQ + q0 + jn * 16 + l15) * DH + ks * 32 + qd * 8);

    floatx4 o[4][4];
#pragma unroll
    for (int ip = 0; ip < 4; ++ip)
#pragma unroll
        for (int jn = 0; jn < 4; ++jn) o[ip][jn] = (floatx4)(0.0f);
    float lsum[4] = {0.0f, 0.0f, 0.0f, 0.0f};

    const u16* kbase = kP + (size_t)(bh * SEQ + wid * 32 + l15) * DH + qd * 8;
    const u16* vbase = vT + (size_t)(bh * 64 + l15) * SEQ + wid * 32 + qd * 8;

    halfx8 kA[2][2], kB[2][2], vA[4], vB[4];
    floatx4 sc[2][4];

    // exp(t): sc -> P in buf, lsum accumulate (sc dead after)
    auto expstore = [&](u16* buf) {
#pragma unroll
        for (int mi = 0; mi < 2; ++mi)
#pragma unroll
            for (int jn = 0; jn < 4; ++jn) {
                float p0 = __builtin_amdgcn_exp2f(sc[mi][jn][0]);
                float p1 = __builtin_amdgcn_exp2f(sc[mi][jn][1]);
                float p2 = __builtin_amdgcn_exp2f(sc[mi][jn][2]);
                float p3 = __builtin_amdgcn_exp2f(sc[mi][jn][3]);
                lsum[jn] += (p0 + p1) + (p2 + p3);
                union { u16x4 u; halfx2 h[2]; } pk;
                pk.h[0] = __builtin_amdgcn_cvt_pkrtz(p0, p1);
                pk.h[1] = __builtin_amdgcn_cvt_pkrtz(p2, p3);
                *(u16x4*)(buf + (jn * 16 + l15) * 36 + mi * 16 + qd * 4) = pk.u;
            }
    };
    // QK: sc = K^T-frag x Q (overwrite in place)
    auto qk = [&](halfx8 (&ak)[2][2]) {
        __builtin_amdgcn_s_setprio(1);
#pragma unroll
        for (int jn = 0; jn < 4; ++jn) {
#pragma unroll
            for (int mi = 0; mi < 2; ++mi) {
                floatx4 z = (floatx4)(0.0f);
                z = __builtin_amdgcn_mfma_f32_16x16x32_f16(ak[mi][0], aq[jn][0], z, 0, 0, 0);
                sc[mi][jn] = __builtin_amdgcn_mfma_f32_16x16x32_f16(ak[mi][1], aq[jn][1], z, 0, 0, 0);
            }
        }
        __builtin_amdgcn_s_setprio(0);
    };
    // PV: read P from buf, accumulate o with V fragments
    auto pv = [&](const u16* buf, halfx8 (&av)[4]) {
#pragma unroll
        for (int jn = 0; jn < 4; ++jn) {
            union { halfx8 h8; u16x4 u4[2]; } bpu;
            bpu.u4[0] = *(const u16x4*)(buf + (jn * 16 + l15) * 36 + qd * 8);
            bpu.u4[1] = *(const u16x4*)(buf + (jn * 16 + l15) * 36 + qd * 8 + 4);
            __builtin_amdgcn_s_setprio(1);
#pragma unroll
            for (int ip = 0; ip < 4; ++ip)
                o[ip][jn] = __builtin_amdgcn_mfma_f32_16x16x32_f16(av[ip], bpu.h8, o[ip][jn], 0, 0, 0);
            __builtin_amdgcn_s_setprio(0);
        }
    };
    auto loadK = [&](halfx8 (&dst)[2][2], int t) {
#pragma unroll
        for (int mi = 0; mi < 2; ++mi)
#pragma unroll
            for (int ks = 0; ks < 2; ++ks)
                dst[mi][ks] = *(const halfx8*)(kbase + (size_t)(((t)&15) * 128 + mi * 16) * DH + ks * 32);
    };
    auto loadV = [&](halfx8 (&dst)[4], int t) {
#pragma unroll
        for (int ip = 0; ip < 4; ++ip)
            dst[ip] = *(const halfx8*)(vbase + (size_t)(ip * 16) * SEQ + ((t)&15) * 128);
    };

    // ---- prologue: QK(0), P(0)->ps0, QK(1); K(2) in kA, V(0) in vA ----
    loadK(kA, 0);
    loadK(kB, 1);
    qk(kA);              // sc = S(0)   (one-time load stall)
    loadK(kA, 2);
    loadV(vA, 0);
    expstore(ps0);       // P(0)
    qk(kB);              // sc = S(1)

    // ---- main loop: iter t does loads(K t+2, V t), exp(t), QK(t+1), PV(t-1) ----
    auto body = [&](int t, u16* bufW, u16* bufR,
                    halfx8 (&kO)[2][2], halfx8 (&kN)[2][2],
                    halfx8 (&vO)[4], halfx8 (&vN)[4]) {
        if (t < 14) loadK(kN, t + 2);
        loadV(vN, t);
        expstore(bufW);          // P(t)
        if (t < 15) qk(kO);      // sc = S(t+1)
        pv(bufR, vO);            // o += P(t-1) x V(t-1)
    };

    body(1, ps1, ps0, kA, kB, vA, vB);
    for (int t = 2; t < 16; t += 2) {
        body(t,     ps0, ps1, kB, kA, vB, vA);
        body(t + 1, ps1, ps0, kA, kB, vA, vB);
    }
    // epilogue of pipeline: PV(15) (P(15) in ps1, V(15) in vB)
    pv(ps1, vB);

    // finish lsum: sum across the 4 qd row-groups (keys within the strip)
#pragma unroll
    for (int jn = 0; jn < 4; ++jn) {
        float v = lsum[jn];
        v += __shfl_xor(v, 16, 64);
        v += __shfl_xor(v, 32, 64);
        lsum[jn] = v;
    }

    // ---- cross-wave sum through LDS (aliases P region; P is dead) ----
    float* Oacc = (float*)smem;                  // [64][68] fp32
    float* la = (float*)smem + 4352;             // [64]

    __syncthreads();
    if (wid == 0) {
#pragma unroll
        for (int jn = 0; jn < 4; ++jn) {
            int q = jn * 16 + l15;
#pragma unroll
            for (int ip = 0; ip < 4; ++ip)
                *(floatx4*)(Oacc + q * 68 + ip * 16 + qd * 4) = o[ip][jn];
            if (qd == 0) la[q] = lsum[jn];
        }
    }
    for (int w = 1; w < 4; ++w) {
        __syncthreads();
        if (wid == w) {
#pragma unroll
            for (int jn = 0; jn < 4; ++jn) {
                int q = jn * 16 + l15;
#pragma unroll
                for (int ip = 0; ip < 4; ++ip) {
                    float* p = Oacc + q * 68 + ip * 16 + qd * 4;
                    *(floatx4*)p = *(floatx4*)p + o[ip][jn];
                }
                if (qd == 0) la[q] += lsum[jn];
            }
        }
    }
    __syncthreads();

    {
        int q = tid >> 2, d0 = (tid & 3) * 16;
        float inv = __builtin_amdgcn_rcpf(la[q]);
        const float* op = Oacc + q * 68 + d0;
        u16x8 pk0, pk1;
#pragma unroll
        for (int r = 0; r < 8; ++r) pk0[r] = f2h(op[r] * inv);
#pragma unroll
        for (int r = 0; r < 8; ++r) pk1[r] = f2h(op[8 + r] * inv);
        u16* dst = attn + (size_t)(b * SEQ + q0 + q) * D_MODEL + h * DH + d0;
        *(u16x8*)dst = pk0;
        *(u16x8*)(dst + 8) = pk1;
    }
}

// ---------------- out GEMM: C[4096][768] = A * WoT^T + bias (fp32 out) ----------------
// 64x64 tile (768 blocks, 3/CU), BK=64, 4 waves each 32x32.

__global__ __launch_bounds__(256) void gemm_out(const u16* __restrict__ A, const u16* __restrict__ Bt,
                                                const float* __restrict__ bias, float* __restrict__ Cout) {
    const int tid = threadIdx.x;
    const int wid = tid >> 6;
    const int lane = tid & 63;
    const int qd = lane >> 4;
    const int l15 = lane & 15;

    const int tn = blockIdx.x * 64;
    const int tm = blockIdx.y * 64;
    const int wm = (wid >> 1) * 32;
    const int wn = (wid & 1) * 32;

    __shared__ alignas(16) u16 As[64 * 64];
    __shared__ alignas(16) u16 Bs[64 * 64];

    floatx4 acc[2][2];
#pragma unroll
    for (int i = 0; i < 2; ++i)
#pragma unroll
        for (int j = 0; j < 2; ++j) acc[i][j] = (floatx4)(0.0f);

    const u16* Ag[2];
    const u16* Bg[2];
#pragma unroll
    for (int rd = 0; rd < 2; ++rd) {
        int s = rd * 256 + tid;
        int r = s >> 3, bl = (s & 7) ^ (r & 7);
        Ag[rd] = A + (size_t)(tm + r) * 768 + bl * 8;
        Bg[rd] = Bt + (size_t)(tn + r) * 768 + bl * 8;
    }

    for (int kb = 0; kb < 768; kb += 64) {
        __syncthreads();
#pragma unroll
        for (int rd = 0; rd < 2; ++rd) {
            gload_lds16(Ag[rd] + kb, As + (size_t)(rd * 256 + tid) * 8);
            gload_lds16(Bg[rd] + kb, Bs + (size_t)(rd * 256 + tid) * 8);
        }
        __syncthreads();

#pragma unroll
        for (int ks = 0; ks < 2; ++ks) {
            halfx8 af[2], bf[2];
#pragma unroll
            for (int i = 0; i < 2; ++i) {
                int r = wm + i * 16 + l15;
                af[i] = *(const halfx8*)(As + r * 64 + (((ks * 4 + qd) ^ (r & 7)) * 8));
                int r2 = wn + i * 16 + l15;
                bf[i] = *(const halfx8*)(Bs + r2 * 64 + (((ks * 4 + qd) ^ (r2 & 7)) * 8));
            }
#pragma unroll
            for (int i = 0; i < 2; ++i)
#pragma unroll
                for (int j = 0; j < 2; ++j)
                    acc[i][j] = __builtin_amdgcn_mfma_f32_16x16x32_f16(af[i], bf[j], acc[i][j], 0, 0, 0);
        }
    }

#pragma unroll
    for (int j = 0; j < 2; ++j) {
        int col = tn + wn + j * 16 + l15;
        float bv = bias[col];
#pragma unroll
        for (int i = 0; i < 2; ++i) {
            int row0 = tm + wm + i * 16 + qd * 4;
#pragma unroll
            for (int r = 0; r < 4; ++r)
                Cout[(size_t)(row0 + r) * 768 + col] = acc[i][j][r] + bv;
        }
    }
}

// ---------------- launch ----------------

extern "C" void kernel_launch(void* const* d_in, const int* in_sizes, int n_in,
                              void* d_out, int out_size, void* d_ws, size_t ws_size,
                              hipStream_t stream) {
    const float* x  = (const float*)d_in[0];
    const float* Wq = (const float*)d_in[1];
    const float* bq = (const float*)d_in[2];
    const float* Wk = (const float*)d_in[3];
    const float* bk = (const float*)d_in[4];
    const float* Wv = (const float*)d_in[5];
    const float* bv = (const float*)d_in[6];
    const float* Wo = (const float*)d_in[7];
    const float* bo = (const float*)d_in[8];

    char* ws = (char*)d_ws;
    size_t off = 0;
    auto take = [&](size_t bytes) -> char* {
        char* p = ws + off;
        off += (bytes + 255) & ~(size_t)255;
        return p;
    };
    u16* WqkvT = (u16*)take((size_t)DQKV * D_MODEL * 2);
    u16* WoT   = (u16*)take((size_t)D_MODEL * D_MODEL * 2);
    u16* qP    = (u16*)take((size_t)MTOK * D_MODEL * 2);
    u16* kP    = (u16*)take((size_t)MTOK * D_MODEL * 2);
    u16* vTb   = (u16*)take((size_t)BATCH * NH * DH * SEQ * 2);
    u16* attn  = (u16*)take((size_t)MTOK * D_MODEL * 2);
    // xh (f16 cast of x) aliases the attn buffer: consumed by gemm_qkv before
    // attn_kernel writes it (stream-ordered).
    u16* xh = attn;

    wprep_kernel<<<576 + (MTOK * D_MODEL / 2048), 256, 0, stream>>>(Wq, Wk, Wv, Wo, x, WqkvT, WoT, xh);
    gemm_qkv<<<dim3(DQKV / 128, MTOK / 64), 256, 0, stream>>>(xh, WqkvT, bq, bk, bv, qP, kP, vTb);
    attn_kernel<<<dim3(BATCH * NH, SEQ / 64), 256, 0, stream>>>(qP, kP, vTb, attn);
    gemm_out<<<dim3(D_MODEL / 64, MTOK / 64), 256, 0, stream>>>(attn, WoT, bo, (float*)d_out);
}

// Round 7
// 178.869 us; speedup vs baseline: 1.1549x; 1.1549x over previous
//
#include <hip/hip_runtime.h>

typedef unsigned short u16;
typedef __fp16 halfx2 __attribute__((ext_vector_type(2)));
typedef __fp16 halfx8 __attribute__((ext_vector_type(8)));
typedef float floatx4 __attribute__((ext_vector_type(4)));
typedef unsigned short u16x4 __attribute__((ext_vector_type(4)));
typedef unsigned short u16x8 __attribute__((ext_vector_type(8)));

#define D_MODEL 768
#define NH 12
#define DH 64
#define SEQ 2048
#define BATCH 2
#define MTOK 4096            // BATCH*SEQ
#define DQKV 2304

__device__ __forceinline__ u16 f2h(float f) {
    __fp16 h = (__fp16)f;
    return __builtin_bit_cast(u16, h);
}

__device__ __forceinline__ void gload_lds16(const void* g, void* l) {
    __builtin_amdgcn_global_load_lds(
        (const __attribute__((address_space(1))) void*)g,
        (__attribute__((address_space(3))) void*)l, 16, 0, 0);
}

// ---------------- prep: W transposes -> f16 [n][k] (576 blocks) + x -> f16 cast (1536 blocks) ----------------

__global__ __launch_bounds__(256) void wprep_kernel(const float* __restrict__ Wq, const float* __restrict__ Wk,
                                                    const float* __restrict__ Wv, const float* __restrict__ Wo,
                                                    const float* __restrict__ x,
                                                    u16* __restrict__ WqkvT, u16* __restrict__ WoT,
                                                    u16* __restrict__ xh) {
    __shared__ u16 t[64][72];
    int bid = blockIdx.x;
    int tid = threadIdx.x;
    if (bid >= 576) {
        // x fp32 -> f16, 2048 elems per block
        int idx = (bid - 576) * 2048 + tid * 8;
        float4 v0 = *(const float4*)(x + idx);
        float4 v1 = *(const float4*)(x + idx + 4);
        union { u16x8 u; halfx2 h[4]; } pk;
        pk.h[0] = __builtin_amdgcn_cvt_pkrtz(v0.x, v0.y);
        pk.h[1] = __builtin_amdgcn_cvt_pkrtz(v0.z, v0.w);
        pk.h[2] = __builtin_amdgcn_cvt_pkrtz(v1.x, v1.y);
        pk.h[3] = __builtin_amdgcn_cvt_pkrtz(v1.z, v1.w);
        *(u16x8*)(xh + idx) = pk.u;
        return;
    }
    int z = bid / 144;
    int t2 = bid % 144;
    int k0 = (t2 / 12) * 64, n0 = (t2 % 12) * 64;
    const float* W = (z == 0) ? Wq : (z == 1) ? Wk : (z == 2) ? Wv : Wo;
    u16* dst = (z < 3) ? (WqkvT + (size_t)z * 768 * 768) : WoT;
#pragma unroll
    for (int p = 0; p < 16; ++p) {
        int idx = p * 256 + tid;
        int kr = idx >> 6, nc = idx & 63;
        t[kr][nc] = f2h(W[(size_t)(k0 + kr) * 768 + n0 + nc]);
    }
    __syncthreads();
#pragma unroll
    for (int p = 0; p < 16; ++p) {
        int idx = p * 256 + tid;
        int nr = idx >> 6, kc = idx & 63;
        dst[(size_t)(n0 + nr) * 768 + k0 + kc] = t[kc][nr];
    }
}

// ---------------- QKV GEMM R18: 128x128 tile (m97 geometry), A from f16 xh via global_load_lds ----------------
// grid (18, 32) = 576 blocks, BK=64, 4 waves each 64x64 (acc[4][4]).
// Proven tile ladder (m92/m103): 64-tile=343 TF vs 128-tile=912 TF at this
// exact structure -> mechanical scale-up of the verified 64x128 kernel.
// Epilogue: Q -> qP[bh][s][64] pre-scaled by 0.125*log2e, K -> kP, V -> vT[bh][d][s].

__global__ __launch_bounds__(256) void gemm_qkv(const u16* __restrict__ xh, const u16* __restrict__ Bt,
                                                const float* __restrict__ bq, const float* __restrict__ bk,
                                                const float* __restrict__ bv,
                                                u16* __restrict__ qP, u16* __restrict__ kP,
                                                u16* __restrict__ vTout) {
    const int tid = threadIdx.x;
    const int wid = tid >> 6;
    const int lane = tid & 63;
    const int qd = lane >> 4;
    const int l15 = lane & 15;

    const int tn = blockIdx.x * 128;   // 18 n-tiles
    const int tm = blockIdx.y * 128;   // 32 m-tiles
    const int wm = (wid >> 1) * 64;
    const int wn = (wid & 1) * 64;

    __shared__ alignas(16) u16 As[128 * 64];   // 16 KB
    __shared__ alignas(16) u16 Bs[128 * 64];   // 16 KB

    floatx4 acc[4][4];
#pragma unroll
    for (int i = 0; i < 4; ++i)
#pragma unroll
        for (int j = 0; j < 4; ++j) acc[i][j] = (floatx4)(0.0f);

    const u16* Ag[4];
    const u16* Bg[4];
#pragma unroll
    for (int rd = 0; rd < 4; ++rd) {
        int s = rd * 256 + tid;
        int r = s >> 3, bl = (s & 7) ^ (r & 7);
        Ag[rd] = xh + (size_t)(tm + r) * 768 + bl * 8;
        Bg[rd] = Bt + (size_t)(tn + r) * 768 + bl * 8;
    }

    for (int kb = 0; kb < 768; kb += 64) {
        __syncthreads();
#pragma unroll
        for (int rd = 0; rd < 4; ++rd)
            gload_lds16(Ag[rd] + kb, As + (size_t)(rd * 256 + tid) * 8);
#pragma unroll
        for (int rd = 0; rd < 4; ++rd)
            gload_lds16(Bg[rd] + kb, Bs + (size_t)(rd * 256 + tid) * 8);
        __syncthreads();

#pragma unroll
        for (int ks = 0; ks < 2; ++ks) {
            halfx8 af[4], bf[4];
#pragma unroll
            for (int i = 0; i < 4; ++i) {
                int r = wm + i * 16 + l15;
                af[i] = *(const halfx8*)(As + r * 64 + (((ks * 4 + qd) ^ (r & 7)) * 8));
            }
#pragma unroll
            for (int j = 0; j < 4; ++j) {
                int r2 = wn + j * 16 + l15;
                bf[j] = *(const halfx8*)(Bs + r2 * 64 + (((ks * 4 + qd) ^ (r2 & 7)) * 8));
            }
#pragma unroll
            for (int i = 0; i < 4; ++i)
#pragma unroll
                for (int j = 0; j < 4; ++j)
                    acc[i][j] = __builtin_amdgcn_mfma_f32_16x16x32_f16(af[i], bf[j], acc[i][j], 0, 0, 0);
        }
    }

    const float cscale = 0.125f * 1.44269504088896340736f;
    const int rgn = (tn < 768) ? 0 : (tn < 1536) ? 1 : 2;   // block-uniform (768/128=6 tile boundary)
    const float* bsrc = (rgn == 0) ? bq : (rgn == 1) ? bk : bv;
#pragma unroll
    for (int j = 0; j < 4; ++j) {
        int col = tn + wn + j * 16 + l15;
        int cl = col - rgn * 768;
        float bvv = bsrc[cl];
        int h = cl >> 6, d = cl & 63;
#pragma unroll
        for (int i = 0; i < 4; ++i) {
            int row0 = tm + wm + i * 16 + qd * 4;
            int b = row0 >> 11, s0 = row0 & 2047;
            u16x4 pk;
#pragma unroll
            for (int r = 0; r < 4; ++r) {
                float v = acc[i][j][r] + bvv;
                if (rgn == 0) v *= cscale;
                pk[r] = f2h(v);
            }
            if (rgn == 2) {
                *(u16x4*)(vTout + ((size_t)(b * NH + h) * 64 + d) * SEQ + s0) = pk;
            } else {
                u16* dst = (rgn == 0) ? qP : kP;
#pragma unroll
                for (int r = 0; r < 4; ++r)
                    dst[((size_t)(b * NH + h) * SEQ + s0 + r) * DH + d] = pk[r];
            }
        }
    }
}

// ---------------- attention R13 (verbatim revert — best measured: 59.1 us) ----------------
// grid = (24 bh fast -> XCD L2 locality, 32 q-tiles of 64). Wave: all 64 q x
// its 32-key strip, 16 iterations. Per iter: issue K/V(t+1) -> exp(t) [VALU]
// -> QK(t+1) [MFMA, setprio] -> P(t) LDS roundtrip -> ones+PV(t) [MFMA,
// setprio]. Unroll-2 ping-pong (scA/scB, avA/avB): no register copies.
// launch_bounds(256,2): 2 blocks/CU, no spills (VGPR 116).

__global__ __launch_bounds__(256, 2) void attn_kernel(const u16* __restrict__ qP, const u16* __restrict__ kP,
                                                      const u16* __restrict__ vT, u16* __restrict__ attn) {
    const int tid = threadIdx.x;
    const int wid = tid >> 6;
    const int lane = tid & 63;
    const int qd = lane >> 4;
    const int l15 = lane & 15;

    const int bh = blockIdx.x;
    const int b = bh / NH, h = bh % NH;
    const int q0 = blockIdx.y * 64;

    __shared__ alignas(16) u16 smem[9216];   // 18 KB: per wave [64][36] P
    u16* ps = smem + wid * 2304;

    halfx8 aq[4][2];
#pragma unroll
    for (int jn = 0; jn < 4; ++jn)
#pragma unroll
        for (int ks = 0; ks < 2; ++ks)
            aq[jn][ks] = *(const halfx8*)(qP + (size_t)(bh * SEQ + q0 + jn * 16 + l15) * DH + ks * 32 + qd * 8);

    halfx8 ones;
#pragma unroll
    for (int j = 0; j < 8; ++j) ones[j] = (__fp16)1.0f;

    floatx4 o[4][4];
#pragma unroll
    for (int ip = 0; ip < 4; ++ip)
#pragma unroll
        for (int jn = 0; jn < 4; ++jn) o[ip][jn] = (floatx4)(0.0f);
    floatx4 lsum[4];
#pragma unroll
    for (int jn = 0; jn < 4; ++jn) lsum[jn] = (floatx4)(0.0f);

    const u16* kbase = kP + (size_t)(bh * SEQ + wid * 32 + l15) * DH + qd * 8;
    const u16* vbase = vT + (size_t)(bh * 64 + l15) * SEQ + wid * 32 + qd * 8;

    // prologue: load K(0), V(0); sc(0) = QK(0)
    halfx8 avA[4], avB[4];
    floatx4 scA[2][4], scB[2][4];
    {
        halfx8 akp[2][2];
#pragma unroll
        for (int mi = 0; mi < 2; ++mi)
#pragma unroll
            for (int ks = 0; ks < 2; ++ks)
                akp[mi][ks] = *(const halfx8*)(kbase + (size_t)(mi * 16) * DH + ks * 32);
#pragma unroll
        for (int ip = 0; ip < 4; ++ip)
            avA[ip] = *(const halfx8*)(vbase + (size_t)(ip * 16) * SEQ);

#pragma unroll
        for (int mi = 0; mi < 2; ++mi)
#pragma unroll
            for (int jn = 0; jn < 4; ++jn) scA[mi][jn] = (floatx4)(0.0f);
#pragma unroll
        for (int ks = 0; ks < 2; ++ks)
#pragma unroll
            for (int mi = 0; mi < 2; ++mi)
#pragma unroll
                for (int jn = 0; jn < 4; ++jn)
                    scA[mi][jn] = __builtin_amdgcn_mfma_f32_16x16x32_f16(akp[mi][ks], aq[jn][ks], scA[mi][jn], 0, 0, 0);
    }

    // body(t): issue K(t+1), V(t+1)->avF; exp(sc(t)=scC); QK(t+1)->scN; PV(t) with avU
    auto body = [&](int kt,
                    floatx4 (&scC)[2][4], floatx4 (&scN)[2][4],
                    halfx8 (&avU)[4], halfx8 (&avF)[4]) {
        const int kt1 = (kt + 1) & 15;   // wrap harmless (valid addresses, values unused)

        halfx8 akn[2][2];
#pragma unroll
        for (int mi = 0; mi < 2; ++mi)
#pragma unroll
            for (int ks = 0; ks < 2; ++ks)
                akn[mi][ks] = *(const halfx8*)(kbase + (size_t)(kt1 * 128 + mi * 16) * DH + ks * 32);
#pragma unroll
        for (int ip = 0; ip < 4; ++ip)
            avF[ip] = *(const halfx8*)(vbase + (size_t)(ip * 16) * SEQ + kt1 * 128);

        // exp(t) from scC (computed last iteration -> no MFMA hazard)
#pragma unroll
        for (int mi = 0; mi < 2; ++mi)
#pragma unroll
            for (int jn = 0; jn < 4; ++jn) {
                float p0 = __builtin_amdgcn_exp2f(scC[mi][jn][0]);
                float p1 = __builtin_amdgcn_exp2f(scC[mi][jn][1]);
                float p2 = __builtin_amdgcn_exp2f(scC[mi][jn][2]);
                float p3 = __builtin_amdgcn_exp2f(scC[mi][jn][3]);
                union { u16x4 u; halfx2 h[2]; } pk;
                pk.h[0] = __builtin_amdgcn_cvt_pkrtz(p0, p1);
                pk.h[1] = __builtin_amdgcn_cvt_pkrtz(p2, p3);
                *(u16x4*)(ps + (jn * 16 + l15) * 36 + mi * 16 + qd * 4) = pk.u;
            }

        // QK(t+1) on the MFMA pipe (overlaps the exp/pack VALU of other waves)
#pragma unroll
        for (int mi = 0; mi < 2; ++mi)
#pragma unroll
            for (int jn = 0; jn < 4; ++jn) scN[mi][jn] = (floatx4)(0.0f);
        __builtin_amdgcn_s_setprio(1);
#pragma unroll
        for (int ks = 0; ks < 2; ++ks)
#pragma unroll
            for (int mi = 0; mi < 2; ++mi)
#pragma unroll
                for (int jn = 0; jn < 4; ++jn)
                    scN[mi][jn] = __builtin_amdgcn_mfma_f32_16x16x32_f16(akn[mi][ks], aq[jn][ks], scN[mi][jn], 0, 0, 0);
        __builtin_amdgcn_s_setprio(0);

        // P(t) fragments (same-wave DS write->read ordering)
        halfx8 bp[4];
#pragma unroll
        for (int jn = 0; jn < 4; ++jn) {
            union { halfx8 h8; u16x4 u4[2]; } bpu;
            bpu.u4[0] = *(const u16x4*)(ps + (jn * 16 + l15) * 36 + qd * 8);
            bpu.u4[1] = *(const u16x4*)(ps + (jn * 16 + l15) * 36 + qd * 8 + 4);
            bp[jn] = bpu.h8;
        }

        __builtin_amdgcn_s_setprio(1);
#pragma unroll
        for (int jn = 0; jn < 4; ++jn)
            lsum[jn] = __builtin_amdgcn_mfma_f32_16x16x32_f16(ones, bp[jn], lsum[jn], 0, 0, 0);
#pragma unroll
        for (int ip = 0; ip < 4; ++ip)
#pragma unroll
            for (int jn = 0; jn < 4; ++jn)
                o[ip][jn] = __builtin_amdgcn_mfma_f32_16x16x32_f16(avU[ip], bp[jn], o[ip][jn], 0, 0, 0);
        __builtin_amdgcn_s_setprio(0);
    };

    for (int kt = 0; kt < 16; kt += 2) {
        body(kt,     scA, scB, avA, avB);
        body(kt + 1, scB, scA, avB, avA);
    }

    // ---- cross-wave sum through LDS (aliases P region; P is dead) ----
    float* Oacc = (float*)smem;                  // [64][68] fp32
    float* la = (float*)smem + 4352;             // [64]

    __syncthreads();
    if (wid == 0) {
#pragma unroll
        for (int jn = 0; jn < 4; ++jn) {
            int q = jn * 16 + l15;
#pragma unroll
            for (int ip = 0; ip < 4; ++ip)
                *(floatx4*)(Oacc + q * 68 + ip * 16 + qd * 4) = o[ip][jn];
            if (qd == 0) la[q] = lsum[jn][0];
        }
    }
    for (int w = 1; w < 4; ++w) {
        __syncthreads();
        if (wid == w) {
#pragma unroll
            for (int jn = 0; jn < 4; ++jn) {
                int q = jn * 16 + l15;
#pragma unroll
                for (int ip = 0; ip < 4; ++ip) {
                    float* p = Oacc + q * 68 + ip * 16 + qd * 4;
                    *(floatx4*)p = *(floatx4*)p + o[ip][jn];
                }
                if (qd == 0) la[q] += lsum[jn][0];
            }
        }
    }
    __syncthreads();

    {
        int q = tid >> 2, d0 = (tid & 3) * 16;
        float inv = __builtin_amdgcn_rcpf(la[q]);
        const float* op = Oacc + q * 68 + d0;
        u16x8 pk0, pk1;
#pragma unroll
        for (int r = 0; r < 8; ++r) pk0[r] = f2h(op[r] * inv);
#pragma unroll
        for (int r = 0; r < 8; ++r) pk1[r] = f2h(op[8 + r] * inv);
        u16* dst = attn + (size_t)(b * SEQ + q0 + q) * D_MODEL + h * DH + d0;
        *(u16x8*)dst = pk0;
        *(u16x8*)(dst + 8) = pk1;
    }
}

// ---------------- out GEMM: C[4096][768] = A * WoT^T + bias (fp32 out) ----------------
// 64x64 tile (768 blocks, 3/CU), BK=64, 4 waves each 32x32.

__global__ __launch_bounds__(256) void gemm_out(const u16* __restrict__ A, const u16* __restrict__ Bt,
                                                const float* __restrict__ bias, float* __restrict__ Cout) {
    const int tid = threadIdx.x;
    const int wid = tid >> 6;
    const int lane = tid & 63;
    const int qd = lane >> 4;
    const int l15 = lane & 15;

    const int tn = blockIdx.x * 64;
    const int tm = blockIdx.y * 64;
    const int wm = (wid >> 1) * 32;
    const int wn = (wid & 1) * 32;

    __shared__ alignas(16) u16 As[64 * 64];
    __shared__ alignas(16) u16 Bs[64 * 64];

    floatx4 acc[2][2];
#pragma unroll
    for (int i = 0; i < 2; ++i)
#pragma unroll
        for (int j = 0; j < 2; ++j) acc[i][j] = (floatx4)(0.0f);

    const u16* Ag[2];
    const u16* Bg[2];
#pragma unroll
    for (int rd = 0; rd < 2; ++rd) {
        int s = rd * 256 + tid;
        int r = s >> 3, bl = (s & 7) ^ (r & 7);
        Ag[rd] = A + (size_t)(tm + r) * 768 + bl * 8;
        Bg[rd] = Bt + (size_t)(tn + r) * 768 + bl * 8;
    }

    for (int kb = 0; kb < 768; kb += 64) {
        __syncthreads();
#pragma unroll
        for (int rd = 0; rd < 2; ++rd) {
            gload_lds16(Ag[rd] + kb, As + (size_t)(rd * 256 + tid) * 8);
            gload_lds16(Bg[rd] + kb, Bs + (size_t)(rd * 256 + tid) * 8);
        }
        __syncthreads();

#pragma unroll
        for (int ks = 0; ks < 2; ++ks) {
            halfx8 af[2], bf[2];
#pragma unroll
            for (int i = 0; i < 2; ++i) {
                int r = wm + i * 16 + l15;
                af[i] = *(const halfx8*)(As + r * 64 + (((ks * 4 + qd) ^ (r & 7)) * 8));
                int r2 = wn + i * 16 + l15;
                bf[i] = *(const halfx8*)(Bs + r2 * 64 + (((ks * 4 + qd) ^ (r2 & 7)) * 8));
            }
#pragma unroll
            for (int i = 0; i < 2; ++i)
#pragma unroll
                for (int j = 0; j < 2; ++j)
                    acc[i][j] = __builtin_amdgcn_mfma_f32_16x16x32_f16(af[i], bf[j], acc[i][j], 0, 0, 0);
        }
    }

#pragma unroll
    for (int j = 0; j < 2; ++j) {
        int col = tn + wn + j * 16 + l15;
        float bv = bias[col];
#pragma unroll
        for (int i = 0; i < 2; ++i) {
            int row0 = tm + wm + i * 16 + qd * 4;
#pragma unroll
            for (int r = 0; r < 4; ++r)
                Cout[(size_t)(row0 + r) * 768 + col] = acc[i][j][r] + bv;
        }
    }
}

// ---------------- launch ----------------

extern "C" void kernel_launch(void* const* d_in, const int* in_sizes, int n_in,
                              void* d_out, int out_size, void* d_ws, size_t ws_size,
                              hipStream_t stream) {
    const float* x  = (const float*)d_in[0];
    const float* Wq = (const float*)d_in[1];
    const float* bq = (const float*)d_in[2];
    const float* Wk = (const float*)d_in[3];
    const float* bk = (const float*)d_in[4];
    const float* Wv = (const float*)d_in[5];
    const float* bv = (const float*)d_in[6];
    const float* Wo = (const float*)d_in[7];
    const float* bo = (const float*)d_in[8];

    char* ws = (char*)d_ws;
    size_t off = 0;
    auto take = [&](size_t bytes) -> char* {
        char* p = ws + off;
        off += (bytes + 255) & ~(size_t)255;
        return p;
    };
    u16* WqkvT = (u16*)take((size_t)DQKV * D_MODEL * 2);
    u16* WoT   = (u16*)take((size_t)D_MODEL * D_MODEL * 2);
    u16* qP    = (u16*)take((size_t)MTOK * D_MODEL * 2);
    u16* kP    = (u16*)take((size_t)MTOK * D_MODEL * 2);
    u16* vTb   = (u16*)take((size_t)BATCH * NH * DH * SEQ * 2);
    u16* attn  = (u16*)take((size_t)MTOK * D_MODEL * 2);
    // xh (f16 cast of x) aliases the attn buffer: consumed by gemm_qkv before
    // attn_kernel writes it (stream-ordered).
    u16* xh = attn;

    wprep_kernel<<<576 + (MTOK * D_MODEL / 2048), 256, 0, stream>>>(Wq, Wk, Wv, Wo, x, WqkvT, WoT, xh);
    gemm_qkv<<<dim3(DQKV / 128, MTOK / 128), 256, 0, stream>>>(xh, WqkvT, bq, bk, bv, qP, kP, vTb);
    attn_kernel<<<dim3(BATCH * NH, SEQ / 64), 256, 0, stream>>>(qP, kP, vTb, attn);
    gemm_out<<<dim3(D_MODEL / 64, MTOK / 64), 256, 0, stream>>>(attn, WoT, bo, (float*)d_out);
}

// Round 8
// 177.425 us; speedup vs baseline: 1.1643x; 1.0081x over previous
//
#include <hip/hip_runtime.h>

typedef unsigned short u16;
typedef __fp16 halfx2 __attribute__((ext_vector_type(2)));
typedef __fp16 halfx8 __attribute__((ext_vector_type(8)));
typedef float floatx4 __attribute__((ext_vector_type(4)));
typedef unsigned short u16x4 __attribute__((ext_vector_type(4)));
typedef unsigned short u16x8 __attribute__((ext_vector_type(8)));

#define D_MODEL 768
#define NH 12
#define DH 64
#define SEQ 2048
#define BATCH 2
#define MTOK 4096            // BATCH*SEQ
#define DQKV 2304

__device__ __forceinline__ u16 f2h(float f) {
    __fp16 h = (__fp16)f;
    return __builtin_bit_cast(u16, h);
}

__device__ __forceinline__ void gload_lds16(const void* g, void* l) {
    __builtin_amdgcn_global_load_lds(
        (const __attribute__((address_space(1))) void*)g,
        (__attribute__((address_space(3))) void*)l, 16, 0, 0);
}

// ---------------- prep: W transposes -> f16 [n][k] (576 blocks) + x -> f16 cast (1536 blocks) ----------------

__global__ __launch_bounds__(256) void wprep_kernel(const float* __restrict__ Wq, const float* __restrict__ Wk,
                                                    const float* __restrict__ Wv, const float* __restrict__ Wo,
                                                    const float* __restrict__ x,
                                                    u16* __restrict__ WqkvT, u16* __restrict__ WoT,
                                                    u16* __restrict__ xh) {
    __shared__ u16 t[64][72];
    int bid = blockIdx.x;
    int tid = threadIdx.x;
    if (bid >= 576) {
        // x fp32 -> f16, 2048 elems per block
        int idx = (bid - 576) * 2048 + tid * 8;
        float4 v0 = *(const float4*)(x + idx);
        float4 v1 = *(const float4*)(x + idx + 4);
        union { u16x8 u; halfx2 h[4]; } pk;
        pk.h[0] = __builtin_amdgcn_cvt_pkrtz(v0.x, v0.y);
        pk.h[1] = __builtin_amdgcn_cvt_pkrtz(v0.z, v0.w);
        pk.h[2] = __builtin_amdgcn_cvt_pkrtz(v1.x, v1.y);
        pk.h[3] = __builtin_amdgcn_cvt_pkrtz(v1.z, v1.w);
        *(u16x8*)(xh + idx) = pk.u;
        return;
    }
    int z = bid / 144;
    int t2 = bid % 144;
    int k0 = (t2 / 12) * 64, n0 = (t2 % 12) * 64;
    const float* W = (z == 0) ? Wq : (z == 1) ? Wk : (z == 2) ? Wv : Wo;
    u16* dst = (z < 3) ? (WqkvT + (size_t)z * 768 * 768) : WoT;
#pragma unroll
    for (int p = 0; p < 16; ++p) {
        int idx = p * 256 + tid;
        int kr = idx >> 6, nc = idx & 63;
        t[kr][nc] = f2h(W[(size_t)(k0 + kr) * 768 + n0 + nc]);
    }
    __syncthreads();
#pragma unroll
    for (int p = 0; p < 16; ++p) {
        int idx = p * 256 + tid;
        int nr = idx >> 6, kc = idx & 63;
        dst[(size_t)(n0 + nr) * 768 + k0 + kc] = t[kc][nr];
    }
}

// ---------------- QKV GEMM (R13 config, best measured): 64x128 tile, A from f16 xh ----------------
// grid (18, 64) = 1152 blocks, BK=64. Epilogue: Q -> qP[bh][s][64] pre-scaled
// by 0.125*log2e, K -> kP[bh][s][64], V -> vT[bh][d][s].

__global__ __launch_bounds__(256) void gemm_qkv(const u16* __restrict__ xh, const u16* __restrict__ Bt,
                                                const float* __restrict__ bq, const float* __restrict__ bk,
                                                const float* __restrict__ bv,
                                                u16* __restrict__ qP, u16* __restrict__ kP,
                                                u16* __restrict__ vTout) {
    const int tid = threadIdx.x;
    const int wid = tid >> 6;
    const int lane = tid & 63;
    const int qd = lane >> 4;
    const int l15 = lane & 15;

    const int tn = blockIdx.x * 128;   // 18 n-tiles
    const int tm = blockIdx.y * 64;    // 64 m-tiles
    const int wm = (wid >> 1) * 32;
    const int wn = (wid & 1) * 64;

    __shared__ alignas(16) u16 As[64 * 64];    // 8 KB
    __shared__ alignas(16) u16 Bs[128 * 64];   // 16 KB

    floatx4 acc[2][4];
#pragma unroll
    for (int i = 0; i < 2; ++i)
#pragma unroll
        for (int j = 0; j < 4; ++j) acc[i][j] = (floatx4)(0.0f);

    const u16* Ag[2];
#pragma unroll
    for (int rd = 0; rd < 2; ++rd) {
        int s = rd * 256 + tid;
        int r = s >> 3, bl = (s & 7) ^ (r & 7);
        Ag[rd] = xh + (size_t)(tm + r) * 768 + bl * 8;
    }
    const u16* Bg[4];
#pragma unroll
    for (int rd = 0; rd < 4; ++rd) {
        int s = rd * 256 + tid;
        int r = s >> 3, bl = (s & 7) ^ (r & 7);
        Bg[rd] = Bt + (size_t)(tn + r) * 768 + bl * 8;
    }

    for (int kb = 0; kb < 768; kb += 64) {
        __syncthreads();
#pragma unroll
        for (int rd = 0; rd < 2; ++rd)
            gload_lds16(Ag[rd] + kb, As + (size_t)(rd * 256 + tid) * 8);
#pragma unroll
        for (int rd = 0; rd < 4; ++rd)
            gload_lds16(Bg[rd] + kb, Bs + (size_t)(rd * 256 + tid) * 8);
        __syncthreads();

#pragma unroll
        for (int ks = 0; ks < 2; ++ks) {
            halfx8 af[2], bf[4];
#pragma unroll
            for (int i = 0; i < 2; ++i) {
                int r = wm + i * 16 + l15;
                af[i] = *(const halfx8*)(As + r * 64 + (((ks * 4 + qd) ^ (r & 7)) * 8));
            }
#pragma unroll
            for (int j = 0; j < 4; ++j) {
                int r2 = wn + j * 16 + l15;
                bf[j] = *(const halfx8*)(Bs + r2 * 64 + (((ks * 4 + qd) ^ (r2 & 7)) * 8));
            }
#pragma unroll
            for (int i = 0; i < 2; ++i)
#pragma unroll
                for (int j = 0; j < 4; ++j)
                    acc[i][j] = __builtin_amdgcn_mfma_f32_16x16x32_f16(af[i], bf[j], acc[i][j], 0, 0, 0);
        }
    }

    const float cscale = 0.125f * 1.44269504088896340736f;
    const int rgn = (tn < 768) ? 0 : (tn < 1536) ? 1 : 2;   // block-uniform
    const float* bsrc = (rgn == 0) ? bq : (rgn == 1) ? bk : bv;
#pragma unroll
    for (int j = 0; j < 4; ++j) {
        int col = tn + wn + j * 16 + l15;
        int cl = col - rgn * 768;
        float bvv = bsrc[cl];
        int h = cl >> 6, d = cl & 63;
#pragma unroll
        for (int i = 0; i < 2; ++i) {
            int row0 = tm + wm + i * 16 + qd * 4;
            int b = row0 >> 11, s0 = row0 & 2047;
            u16x4 pk;
#pragma unroll
            for (int r = 0; r < 4; ++r) {
                float v = acc[i][j][r] + bvv;
                if (rgn == 0) v *= cscale;
                pk[r] = f2h(v);
            }
            if (rgn == 2) {
                *(u16x4*)(vTout + ((size_t)(b * NH + h) * 64 + d) * SEQ + s0) = pk;
            } else {
                u16* dst = (rgn == 0) ? qP : kP;
#pragma unroll
                for (int r = 0; r < 4; ++r)
                    dst[((size_t)(b * NH + h) * SEQ + s0 + r) * DH + d] = pk[r];
            }
        }
    }
}

// ---------------- attention R19: R13 + K prefetch at distance 2 (single-variable change) ----------------
// R13's only sub-iteration-slack dependence was K(t+1): loaded top of body(t),
// consumed by QK(t+1) in the SAME body (~150-180 cy later). K/V come from
// other XCDs' L2 -> served by L3 (~500-700 cy) -> every iteration ate an L3
// round-trip. Fix: persistent kA/kB ping-pong; body(t) issues K(t+2) and QK
// consumes K(t+1) loaded one FULL iteration ago. +16 VGPR vs R13 (~196->212
// unified, fits launch_bounds(256,2) with headroom -> no spills; tripwire:
// WRITE_SIZE must stay 6144 KB). V already distance-1 (full-iter slack).
// Everything else verbatim R13 (59.2 us measured).

__global__ __launch_bounds__(256, 2) void attn_kernel(const u16* __restrict__ qP, const u16* __restrict__ kP,
                                                      const u16* __restrict__ vT, u16* __restrict__ attn) {
    const int tid = threadIdx.x;
    const int wid = tid >> 6;
    const int lane = tid & 63;
    const int qd = lane >> 4;
    const int l15 = lane & 15;

    const int bh = blockIdx.x;
    const int b = bh / NH, h = bh % NH;
    const int q0 = blockIdx.y * 64;

    __shared__ alignas(16) u16 smem[9216];   // 18 KB: per wave [64][36] P
    u16* ps = smem + wid * 2304;

    halfx8 aq[4][2];
#pragma unroll
    for (int jn = 0; jn < 4; ++jn)
#pragma unroll
        for (int ks = 0; ks < 2; ++ks)
            aq[jn][ks] = *(const halfx8*)(qP + (size_t)(bh * SEQ + q0 + jn * 16 + l15) * DH + ks * 32 + qd * 8);

    halfx8 ones;
#pragma unroll
    for (int j = 0; j < 8; ++j) ones[j] = (__fp16)1.0f;

    floatx4 o[4][4];
#pragma unroll
    for (int ip = 0; ip < 4; ++ip)
#pragma unroll
        for (int jn = 0; jn < 4; ++jn) o[ip][jn] = (floatx4)(0.0f);
    floatx4 lsum[4];
#pragma unroll
    for (int jn = 0; jn < 4; ++jn) lsum[jn] = (floatx4)(0.0f);

    const u16* kbase = kP + (size_t)(bh * SEQ + wid * 32 + l15) * DH + qd * 8;
    const u16* vbase = vT + (size_t)(bh * 64 + l15) * SEQ + wid * 32 + qd * 8;

    halfx8 kA[2][2], kB[2][2];
    halfx8 avA[4], avB[4];
    floatx4 scA[2][4], scB[2][4];

    auto loadK = [&](halfx8 (&dst)[2][2], int t) {
#pragma unroll
        for (int mi = 0; mi < 2; ++mi)
#pragma unroll
            for (int ks = 0; ks < 2; ++ks)
                dst[mi][ks] = *(const halfx8*)(kbase + (size_t)((t & 15) * 128 + mi * 16) * DH + ks * 32);
    };

    // prologue: K(0)->kA, K(1)->kB, V(0)->avA; sc(0) = QK(0) with kA (one-time stall)
    loadK(kA, 0);
    loadK(kB, 1);
#pragma unroll
    for (int ip = 0; ip < 4; ++ip)
        avA[ip] = *(const halfx8*)(vbase + (size_t)(ip * 16) * SEQ);

#pragma unroll
    for (int mi = 0; mi < 2; ++mi)
#pragma unroll
        for (int jn = 0; jn < 4; ++jn) scA[mi][jn] = (floatx4)(0.0f);
#pragma unroll
    for (int ks = 0; ks < 2; ++ks)
#pragma unroll
        for (int mi = 0; mi < 2; ++mi)
#pragma unroll
            for (int jn = 0; jn < 4; ++jn)
                scA[mi][jn] = __builtin_amdgcn_mfma_f32_16x16x32_f16(kA[mi][ks], aq[jn][ks], scA[mi][jn], 0, 0, 0);

    // body(t): issue K(t+2)->kF, V(t+1)->avF; exp(sc(t)=scC); QK(t+1) with kU
    // (loaded one full iteration ago); PV(t) with avU.
    auto body = [&](int kt,
                    floatx4 (&scC)[2][4], floatx4 (&scN)[2][4],
                    halfx8 (&avU)[4], halfx8 (&avF)[4],
                    halfx8 (&kU)[2][2], halfx8 (&kF)[2][2]) {
        const int kt1 = (kt + 1) & 15;   // wrap harmless (valid addresses, values unused)

        loadK(kF, kt + 2);
#pragma unroll
        for (int ip = 0; ip < 4; ++ip)
            avF[ip] = *(const halfx8*)(vbase + (size_t)(ip * 16) * SEQ + kt1 * 128);

        // exp(t) from scC (computed last iteration -> no MFMA hazard)
#pragma unroll
        for (int mi = 0; mi < 2; ++mi)
#pragma unroll
            for (int jn = 0; jn < 4; ++jn) {
                float p0 = __builtin_amdgcn_exp2f(scC[mi][jn][0]);
                float p1 = __builtin_amdgcn_exp2f(scC[mi][jn][1]);
                float p2 = __builtin_amdgcn_exp2f(scC[mi][jn][2]);
                float p3 = __builtin_amdgcn_exp2f(scC[mi][jn][3]);
                union { u16x4 u; halfx2 h[2]; } pk;
                pk.h[0] = __builtin_amdgcn_cvt_pkrtz(p0, p1);
                pk.h[1] = __builtin_amdgcn_cvt_pkrtz(p2, p3);
                *(u16x4*)(ps + (jn * 16 + l15) * 36 + mi * 16 + qd * 4) = pk.u;
            }

        // QK(t+1) with kU = K(t+1), loaded a full iteration ago (slack >> L3 latency)
#pragma unroll
        for (int mi = 0; mi < 2; ++mi)
#pragma unroll
            for (int jn = 0; jn < 4; ++jn) scN[mi][jn] = (floatx4)(0.0f);
        __builtin_amdgcn_s_setprio(1);
#pragma unroll
        for (int ks = 0; ks < 2; ++ks)
#pragma unroll
            for (int mi = 0; mi < 2; ++mi)
#pragma unroll
                for (int jn = 0; jn < 4; ++jn)
                    scN[mi][jn] = __builtin_amdgcn_mfma_f32_16x16x32_f16(kU[mi][ks], aq[jn][ks], scN[mi][jn], 0, 0, 0);
        __builtin_amdgcn_s_setprio(0);

        // P(t) fragments (same-wave DS write->read ordering)
        halfx8 bp[4];
#pragma unroll
        for (int jn = 0; jn < 4; ++jn) {
            union { halfx8 h8; u16x4 u4[2]; } bpu;
            bpu.u4[0] = *(const u16x4*)(ps + (jn * 16 + l15) * 36 + qd * 8);
            bpu.u4[1] = *(const u16x4*)(ps + (jn * 16 + l15) * 36 + qd * 8 + 4);
            bp[jn] = bpu.h8;
        }

        __builtin_amdgcn_s_setprio(1);
#pragma unroll
        for (int jn = 0; jn < 4; ++jn)
            lsum[jn] = __builtin_amdgcn_mfma_f32_16x16x32_f16(ones, bp[jn], lsum[jn], 0, 0, 0);
#pragma unroll
        for (int ip = 0; ip < 4; ++ip)
#pragma unroll
            for (int jn = 0; jn < 4; ++jn)
                o[ip][jn] = __builtin_amdgcn_mfma_f32_16x16x32_f16(avU[ip], bp[jn], o[ip][jn], 0, 0, 0);
        __builtin_amdgcn_s_setprio(0);
    };

    for (int kt = 0; kt < 16; kt += 2) {
        body(kt,     scA, scB, avA, avB, kB, kA);
        body(kt + 1, scB, scA, avB, avA, kA, kB);
    }

    // ---- cross-wave sum through LDS (aliases P region; P is dead) ----
    float* Oacc = (float*)smem;                  // [64][68] fp32
    float* la = (float*)smem + 4352;             // [64]

    __syncthreads();
    if (wid == 0) {
#pragma unroll
        for (int jn = 0; jn < 4; ++jn) {
            int q = jn * 16 + l15;
#pragma unroll
            for (int ip = 0; ip < 4; ++ip)
                *(floatx4*)(Oacc + q * 68 + ip * 16 + qd * 4) = o[ip][jn];
            if (qd == 0) la[q] = lsum[jn][0];
        }
    }
    for (int w = 1; w < 4; ++w) {
        __syncthreads();
        if (wid == w) {
#pragma unroll
            for (int jn = 0; jn < 4; ++jn) {
                int q = jn * 16 + l15;
#pragma unroll
                for (int ip = 0; ip < 4; ++ip) {
                    float* p = Oacc + q * 68 + ip * 16 + qd * 4;
                    *(floatx4*)p = *(floatx4*)p + o[ip][jn];
                }
                if (qd == 0) la[q] += lsum[jn][0];
            }
        }
    }
    __syncthreads();

    {
        int q = tid >> 2, d0 = (tid & 3) * 16;
        float inv = __builtin_amdgcn_rcpf(la[q]);
        const float* op = Oacc + q * 68 + d0;
        u16x8 pk0, pk1;
#pragma unroll
        for (int r = 0; r < 8; ++r) pk0[r] = f2h(op[r] * inv);
#pragma unroll
        for (int r = 0; r < 8; ++r) pk1[r] = f2h(op[8 + r] * inv);
        u16* dst = attn + (size_t)(b * SEQ + q0 + q) * D_MODEL + h * DH + d0;
        *(u16x8*)dst = pk0;
        *(u16x8*)(dst + 8) = pk1;
    }
}

// ---------------- out GEMM: C[4096][768] = A * WoT^T + bias (fp32 out) ----------------
// 64x64 tile (768 blocks, 3/CU), BK=64, 4 waves each 32x32.

__global__ __launch_bounds__(256) void gemm_out(const u16* __restrict__ A, const u16* __restrict__ Bt,
                                                const float* __restrict__ bias, float* __restrict__ Cout) {
    const int tid = threadIdx.x;
    const int wid = tid >> 6;
    const int lane = tid & 63;
    const int qd = lane >> 4;
    const int l15 = lane & 15;

    const int tn = blockIdx.x * 64;
    const int tm = blockIdx.y * 64;
    const int wm = (wid >> 1) * 32;
    const int wn = (wid & 1) * 32;

    __shared__ alignas(16) u16 As[64 * 64];
    __shared__ alignas(16) u16 Bs[64 * 64];

    floatx4 acc[2][2];
#pragma unroll
    for (int i = 0; i < 2; ++i)
#pragma unroll
        for (int j = 0; j < 2; ++j) acc[i][j] = (floatx4)(0.0f);

    const u16* Ag[2];
    const u16* Bg[2];
#pragma unroll
    for (int rd = 0; rd < 2; ++rd) {
        int s = rd * 256 + tid;
        int r = s >> 3, bl = (s & 7) ^ (r & 7);
        Ag[rd] = A + (size_t)(tm + r) * 768 + bl * 8;
        Bg[rd] = Bt + (size_t)(tn + r) * 768 + bl * 8;
    }

    for (int kb = 0; kb < 768; kb += 64) {
        __syncthreads();
#pragma unroll
        for (int rd = 0; rd < 2; ++rd) {
            gload_lds16(Ag[rd] + kb, As + (size_t)(rd * 256 + tid) * 8);
            gload_lds16(Bg[rd] + kb, Bs + (size_t)(rd * 256 + tid) * 8);
        }
        __syncthreads();

#pragma unroll
        for (int ks = 0; ks < 2; ++ks) {
            halfx8 af[2], bf[2];
#pragma unroll
            for (int i = 0; i < 2; ++i) {
                int r = wm + i * 16 + l15;
                af[i] = *(const halfx8*)(As + r * 64 + (((ks * 4 + qd) ^ (r & 7)) * 8));
                int r2 = wn + i * 16 + l15;
                bf[i] = *(const halfx8*)(Bs + r2 * 64 + (((ks * 4 + qd) ^ (r2 & 7)) * 8));
            }
#pragma unroll
            for (int i = 0; i < 2; ++i)
#pragma unroll
                for (int j = 0; j < 2; ++j)
                    acc[i][j] = __builtin_amdgcn_mfma_f32_16x16x32_f16(af[i], bf[j], acc[i][j], 0, 0, 0);
        }
    }

#pragma unroll
    for (int j = 0; j < 2; ++j) {
        int col = tn + wn + j * 16 + l15;
        float bv = bias[col];
#pragma unroll
        for (int i = 0; i < 2; ++i) {
            int row0 = tm + wm + i * 16 + qd * 4;
#pragma unroll
            for (int r = 0; r < 4; ++r)
                Cout[(size_t)(row0 + r) * 768 + col] = acc[i][j][r] + bv;
        }
    }
}

// ---------------- launch ----------------

extern "C" void kernel_launch(void* const* d_in, const int* in_sizes, int n_in,
                              void* d_out, int out_size, void* d_ws, size_t ws_size,
                              hipStream_t stream) {
    const float* x  = (const float*)d_in[0];
    const float* Wq = (const float*)d_in[1];
    const float* bq = (const float*)d_in[2];
    const float* Wk = (const float*)d_in[3];
    const float* bk = (const float*)d_in[4];
    const float* Wv = (const float*)d_in[5];
    const float* bv = (const float*)d_in[6];
    const float* Wo = (const float*)d_in[7];
    const float* bo = (const float*)d_in[8];

    char* ws = (char*)d_ws;
    size_t off = 0;
    auto take = [&](size_t bytes) -> char* {
        char* p = ws + off;
        off += (bytes + 255) & ~(size_t)255;
        return p;
    };
    u16* WqkvT = (u16*)take((size_t)DQKV * D_MODEL * 2);
    u16* WoT   = (u16*)take((size_t)D_MODEL * D_MODEL * 2);
    u16* qP    = (u16*)take((size_t)MTOK * D_MODEL * 2);
    u16* kP    = (u16*)take((size_t)MTOK * D_MODEL * 2);
    u16* vTb   = (u16*)take((size_t)BATCH * NH * DH * SEQ * 2);
    u16* attn  = (u16*)take((size_t)MTOK * D_MODEL * 2);
    // xh (f16 cast of x) aliases the attn buffer: consumed by gemm_qkv before
    // attn_kernel writes it (stream-ordered).
    u16* xh = attn;

    wprep_kernel<<<576 + (MTOK * D_MODEL / 2048), 256, 0, stream>>>(Wq, Wk, Wv, Wo, x, WqkvT, WoT, xh);
    gemm_qkv<<<dim3(DQKV / 128, MTOK / 64), 256, 0, stream>>>(xh, WqkvT, bq, bk, bv, qP, kP, vTb);
    attn_kernel<<<dim3(BATCH * NH, SEQ / 64), 256, 0, stream>>>(qP, kP, vTb, attn);
    gemm_out<<<dim3(D_MODEL / 64, MTOK / 64), 256, 0, stream>>>(attn, WoT, bo, (float*)d_out);
}

// Round 9
// 172.227 us; speedup vs baseline: 1.1995x; 1.0302x over previous
//
#include <hip/hip_runtime.h>

typedef unsigned short u16;
typedef __fp16 halfx2 __attribute__((ext_vector_type(2)));
typedef __fp16 halfx8 __attribute__((ext_vector_type(8)));
typedef float floatx4 __attribute__((ext_vector_type(4)));
typedef unsigned short u16x4 __attribute__((ext_vector_type(4)));
typedef unsigned short u16x8 __attribute__((ext_vector_type(8)));

#define D_MODEL 768
#define NH 12
#define DH 64
#define SEQ 2048
#define BATCH 2
#define MTOK 4096            // BATCH*SEQ
#define DQKV 2304

__device__ __forceinline__ u16 f2h(float f) {
    __fp16 h = (__fp16)f;
    return __builtin_bit_cast(u16, h);
}

__device__ __forceinline__ void gload_lds16(const void* g, void* l) {
    __builtin_amdgcn_global_load_lds(
        (const __attribute__((address_space(1))) void*)g,
        (__attribute__((address_space(3))) void*)l, 16, 0, 0);
}

// ---------------- prep: W transposes -> f16 [n][k] (576 blocks) + x -> f16 cast (1536 blocks) ----------------
// R20: LDS pad 72 -> 66 u16 (stride 33 dwords, gcd(33,32)=1) -> transpose
// reads conflict-free (72 gave stride 36 dw, 8-way conflict x16 iterations).

__global__ __launch_bounds__(256) void wprep_kernel(const float* __restrict__ Wq, const float* __restrict__ Wk,
                                                    const float* __restrict__ Wv, const float* __restrict__ Wo,
                                                    const float* __restrict__ x,
                                                    u16* __restrict__ WqkvT, u16* __restrict__ WoT,
                                                    u16* __restrict__ xh) {
    __shared__ u16 t[64][66];
    int bid = blockIdx.x;
    int tid = threadIdx.x;
    if (bid >= 576) {
        // x fp32 -> f16, 2048 elems per block
        int idx = (bid - 576) * 2048 + tid * 8;
        float4 v0 = *(const float4*)(x + idx);
        float4 v1 = *(const float4*)(x + idx + 4);
        union { u16x8 u; halfx2 h[4]; } pk;
        pk.h[0] = __builtin_amdgcn_cvt_pkrtz(v0.x, v0.y);
        pk.h[1] = __builtin_amdgcn_cvt_pkrtz(v0.z, v0.w);
        pk.h[2] = __builtin_amdgcn_cvt_pkrtz(v1.x, v1.y);
        pk.h[3] = __builtin_amdgcn_cvt_pkrtz(v1.z, v1.w);
        *(u16x8*)(xh + idx) = pk.u;
        return;
    }
    int z = bid / 144;
    int t2 = bid % 144;
    int k0 = (t2 / 12) * 64, n0 = (t2 % 12) * 64;
    const float* W = (z == 0) ? Wq : (z == 1) ? Wk : (z == 2) ? Wv : Wo;
    u16* dst = (z < 3) ? (WqkvT + (size_t)z * 768 * 768) : WoT;
#pragma unroll
    for (int p = 0; p < 16; ++p) {
        int idx = p * 256 + tid;
        int kr = idx >> 6, nc = idx & 63;
        t[kr][nc] = f2h(W[(size_t)(k0 + kr) * 768 + n0 + nc]);
    }
    __syncthreads();
#pragma unroll
    for (int p = 0; p < 16; ++p) {
        int idx = p * 256 + tid;
        int nr = idx >> 6, kc = idx & 63;
        dst[(size_t)(n0 + nr) * 768 + k0 + kc] = t[kc][nr];
    }
}

// ---------------- QKV GEMM: 64x128 tile, A from f16 xh; R20 coalesced epilogue ----------------
// grid (18, 64) = 1152 blocks, BK=64. Main loop unchanged (best measured).
// Epilogue: stage the 64-token x 128-col f16 tile into LDS [64][132] (pad ->
// stage writes land 2 lanes/bank = free), barrier, then coalesced readout:
//   Q/K: u16x8 per lane, 128B contiguous per (token, head) row.
//   V:   u16x4 token-quads along s, 128B contiguous per d-column.
// Replaces 32 scalar u16 global stores (Q/K, 32B segments) and 8B stride-4KB
// stores (V) per wave.

__global__ __launch_bounds__(256) void gemm_qkv(const u16* __restrict__ xh, const u16* __restrict__ Bt,
                                                const float* __restrict__ bq, const float* __restrict__ bk,
                                                const float* __restrict__ bv,
                                                u16* __restrict__ qP, u16* __restrict__ kP,
                                                u16* __restrict__ vTout) {
    const int tid = threadIdx.x;
    const int wid = tid >> 6;
    const int lane = tid & 63;
    const int qd = lane >> 4;
    const int l15 = lane & 15;

    const int tn = blockIdx.x * 128;   // 18 n-tiles
    const int tm = blockIdx.y * 64;    // 64 m-tiles
    const int wm = (wid >> 1) * 32;
    const int wn = (wid & 1) * 64;

    __shared__ alignas(16) u16 sm[12288];      // As 64x64 (4096) + Bs 128x64 (8192); epilogue reuses as T[64][132]
    u16* As = sm;
    u16* Bs = sm + 4096;

    floatx4 acc[2][4];
#pragma unroll
    for (int i = 0; i < 2; ++i)
#pragma unroll
        for (int j = 0; j < 4; ++j) acc[i][j] = (floatx4)(0.0f);

    const u16* Ag[2];
#pragma unroll
    for (int rd = 0; rd < 2; ++rd) {
        int s = rd * 256 + tid;
        int r = s >> 3, bl = (s & 7) ^ (r & 7);
        Ag[rd] = xh + (size_t)(tm + r) * 768 + bl * 8;
    }
    const u16* Bg[4];
#pragma unroll
    for (int rd = 0; rd < 4; ++rd) {
        int s = rd * 256 + tid;
        int r = s >> 3, bl = (s & 7) ^ (r & 7);
        Bg[rd] = Bt + (size_t)(tn + r) * 768 + bl * 8;
    }

    for (int kb = 0; kb < 768; kb += 64) {
        __syncthreads();
#pragma unroll
        for (int rd = 0; rd < 2; ++rd)
            gload_lds16(Ag[rd] + kb, As + (size_t)(rd * 256 + tid) * 8);
#pragma unroll
        for (int rd = 0; rd < 4; ++rd)
            gload_lds16(Bg[rd] + kb, Bs + (size_t)(rd * 256 + tid) * 8);
        __syncthreads();

#pragma unroll
        for (int ks = 0; ks < 2; ++ks) {
            halfx8 af[2], bf[4];
#pragma unroll
            for (int i = 0; i < 2; ++i) {
                int r = wm + i * 16 + l15;
                af[i] = *(const halfx8*)(As + r * 64 + (((ks * 4 + qd) ^ (r & 7)) * 8));
            }
#pragma unroll
            for (int j = 0; j < 4; ++j) {
                int r2 = wn + j * 16 + l15;
                bf[j] = *(const halfx8*)(Bs + r2 * 64 + (((ks * 4 + qd) ^ (r2 & 7)) * 8));
            }
#pragma unroll
            for (int i = 0; i < 2; ++i)
#pragma unroll
                for (int j = 0; j < 4; ++j)
                    acc[i][j] = __builtin_amdgcn_mfma_f32_16x16x32_f16(af[i], bf[j], acc[i][j], 0, 0, 0);
        }
    }

    const float cscale = 0.125f * 1.44269504088896340736f;
    const int rgn = (tn < 768) ? 0 : (tn < 1536) ? 1 : 2;   // block-uniform (tn step 128; 768/128=6)
    const float* bsrc = (rgn == 0) ? bq : (rgn == 1) ? bk : bv;

    __syncthreads();   // all waves done with As/Bs before T aliases them
    u16* T = sm;       // [64 tokens][132 cols]

    // stage acc (+bias, Q pre-scale) into T — pad 132: qd row-groups land on
    // disjoint bank octets, 2 lanes/bank = free
#pragma unroll
    for (int j = 0; j < 4; ++j) {
        int col = wn + j * 16 + l15;
        int cl = tn + col - rgn * 768;
        float bvv = bsrc[cl];
#pragma unroll
        for (int i = 0; i < 2; ++i) {
            int row0 = wm + i * 16 + qd * 4;
#pragma unroll
            for (int r = 0; r < 4; ++r) {
                float v = acc[i][j][r] + bvv;
                if (rgn == 0) v *= cscale;
                T[(size_t)(row0 + r) * 132 + col] = f2h(v);
            }
        }
    }
    __syncthreads();

    const int hbase = (tn - rgn * 768) >> 6;   // head index of col 0 (even)
    const int b = tm >> 11, s0 = tm & 2047;    // block-uniform (64-token tile within one batch)

    if (rgn < 2) {
        u16* dst = (rgn == 0) ? qP : kP;
        // 64 tokens x 2 heads x 64 d = 1024 x 16B chunks; 4 iterations of 256 lanes.
        // lane -> (token, hh, sub): contiguous 128B per (token, head) row.
#pragma unroll
        for (int it = 0; it < 4; ++it) {
            int idx = it * 256 + tid;
            int token = idx >> 4, rem = idx & 15;
            int hh = rem >> 3, sub = rem & 7;
            u16x8 v = *(const u16x8*)(T + (size_t)token * 132 + hh * 64 + sub * 8);
            *(u16x8*)(dst + ((size_t)(b * NH + hbase + hh) * SEQ + s0 + token) * DH + sub * 8) = v;
        }
    } else {
        // V: vT[bh][d][s] — per d-column, 64 tokens contiguous along s.
        // lane -> (col c, token-quad tq): u16x4 stores, 128B contiguous per column.
#pragma unroll
        for (int it = 0; it < 8; ++it) {
            int idx = it * 256 + tid;
            int c = idx >> 4, tq = (idx & 15) * 4;
            u16x4 v;
#pragma unroll
            for (int k = 0; k < 4; ++k) v[k] = T[(size_t)(tq + k) * 132 + c];
            int h = hbase + (c >> 6), d = c & 63;
            *(u16x4*)(vTout + ((size_t)(b * NH + h) * 64 + d) * SEQ + s0 + tq) = v;
        }
    }
}

// ---------------- attention R13 (verbatim — best measured: 59.2 us) ----------------
// grid = (24 bh fast -> XCD L2 locality, 32 q-tiles of 64). Wave: all 64 q x
// its 32-key strip, 16 iterations. Per iter: issue K/V(t+1) -> exp(t) [VALU]
// -> QK(t+1) [MFMA, setprio] -> P(t) LDS roundtrip -> ones+PV(t) [MFMA,
// setprio]. Unroll-2 ping-pong (scA/scB, avA/avB): no register copies.
// launch_bounds(256,2): 2 blocks/CU, no spills (VGPR 116).
// NOTE (R12-R19 post-mortems): occupancy 17-32%, K prefetch distance 1->2,
// shared/swizzled P, d-split PV all measured FLAT or worse. ~59 us is this
// decomposition's empirical floor; residual stall unexplained by counters.

__global__ __launch_bounds__(256, 2) void attn_kernel(const u16* __restrict__ qP, const u16* __restrict__ kP,
                                                      const u16* __restrict__ vT, u16* __restrict__ attn) {
    const int tid = threadIdx.x;
    const int wid = tid >> 6;
    const int lane = tid & 63;
    const int qd = lane >> 4;
    const int l15 = lane & 15;

    const int bh = blockIdx.x;
    const int b = bh / NH, h = bh % NH;
    const int q0 = blockIdx.y * 64;

    __shared__ alignas(16) u16 smem[9216];   // 18 KB: per wave [64][36] P
    u16* ps = smem + wid * 2304;

    halfx8 aq[4][2];
#pragma unroll
    for (int jn = 0; jn < 4; ++jn)
#pragma unroll
        for (int ks = 0; ks < 2; ++ks)
            aq[jn][ks] = *(const halfx8*)(qP + (size_t)(bh * SEQ + q0 + jn * 16 + l15) * DH + ks * 32 + qd * 8);

    halfx8 ones;
#pragma unroll
    for (int j = 0; j < 8; ++j) ones[j] = (__fp16)1.0f;

    floatx4 o[4][4];
#pragma unroll
    for (int ip = 0; ip < 4; ++ip)
#pragma unroll
        for (int jn = 0; jn < 4; ++jn) o[ip][jn] = (floatx4)(0.0f);
    floatx4 lsum[4];
#pragma unroll
    for (int jn = 0; jn < 4; ++jn) lsum[jn] = (floatx4)(0.0f);

    const u16* kbase = kP + (size_t)(bh * SEQ + wid * 32 + l15) * DH + qd * 8;
    const u16* vbase = vT + (size_t)(bh * 64 + l15) * SEQ + wid * 32 + qd * 8;

    // prologue: load K(0), V(0); sc(0) = QK(0)
    halfx8 avA[4], avB[4];
    floatx4 scA[2][4], scB[2][4];
    {
        halfx8 akp[2][2];
#pragma unroll
        for (int mi = 0; mi < 2; ++mi)
#pragma unroll
            for (int ks = 0; ks < 2; ++ks)
                akp[mi][ks] = *(const halfx8*)(kbase + (size_t)(mi * 16) * DH + ks * 32);
#pragma unroll
        for (int ip = 0; ip < 4; ++ip)
            avA[ip] = *(const halfx8*)(vbase + (size_t)(ip * 16) * SEQ);

#pragma unroll
        for (int mi = 0; mi < 2; ++mi)
#pragma unroll
            for (int jn = 0; jn < 4; ++jn) scA[mi][jn] = (floatx4)(0.0f);
#pragma unroll
        for (int ks = 0; ks < 2; ++ks)
#pragma unroll
            for (int mi = 0; mi < 2; ++mi)
#pragma unroll
                for (int jn = 0; jn < 4; ++jn)
                    scA[mi][jn] = __builtin_amdgcn_mfma_f32_16x16x32_f16(akp[mi][ks], aq[jn][ks], scA[mi][jn], 0, 0, 0);
    }

    // body(t): issue K(t+1), V(t+1)->avF; exp(sc(t)=scC); QK(t+1)->scN; PV(t) with avU
    auto body = [&](int kt,
                    floatx4 (&scC)[2][4], floatx4 (&scN)[2][4],
                    halfx8 (&avU)[4], halfx8 (&avF)[4]) {
        const int kt1 = (kt + 1) & 15;   // wrap harmless (valid addresses, values unused)

        halfx8 akn[2][2];
#pragma unroll
        for (int mi = 0; mi < 2; ++mi)
#pragma unroll
            for (int ks = 0; ks < 2; ++ks)
                akn[mi][ks] = *(const halfx8*)(kbase + (size_t)(kt1 * 128 + mi * 16) * DH + ks * 32);
#pragma unroll
        for (int ip = 0; ip < 4; ++ip)
            avF[ip] = *(const halfx8*)(vbase + (size_t)(ip * 16) * SEQ + kt1 * 128);

        // exp(t) from scC (computed last iteration -> no MFMA hazard)
#pragma unroll
        for (int mi = 0; mi < 2; ++mi)
#pragma unroll
            for (int jn = 0; jn < 4; ++jn) {
                float p0 = __builtin_amdgcn_exp2f(scC[mi][jn][0]);
                float p1 = __builtin_amdgcn_exp2f(scC[mi][jn][1]);
                float p2 = __builtin_amdgcn_exp2f(scC[mi][jn][2]);
                float p3 = __builtin_amdgcn_exp2f(scC[mi][jn][3]);
                union { u16x4 u; halfx2 h[2]; } pk;
                pk.h[0] = __builtin_amdgcn_cvt_pkrtz(p0, p1);
                pk.h[1] = __builtin_amdgcn_cvt_pkrtz(p2, p3);
                *(u16x4*)(ps + (jn * 16 + l15) * 36 + mi * 16 + qd * 4) = pk.u;
            }

        // QK(t+1) on the MFMA pipe (overlaps the exp/pack VALU of other waves)
#pragma unroll
        for (int mi = 0; mi < 2; ++mi)
#pragma unroll
            for (int jn = 0; jn < 4; ++jn) scN[mi][jn] = (floatx4)(0.0f);
        __builtin_amdgcn_s_setprio(1);
#pragma unroll
        for (int ks = 0; ks < 2; ++ks)
#pragma unroll
            for (int mi = 0; mi < 2; ++mi)
#pragma unroll
                for (int jn = 0; jn < 4; ++jn)
                    scN[mi][jn] = __builtin_amdgcn_mfma_f32_16x16x32_f16(akn[mi][ks], aq[jn][ks], scN[mi][jn], 0, 0, 0);
        __builtin_amdgcn_s_setprio(0);

        // P(t) fragments (same-wave DS write->read ordering)
        halfx8 bp[4];
#pragma unroll
        for (int jn = 0; jn < 4; ++jn) {
            union { halfx8 h8; u16x4 u4[2]; } bpu;
            bpu.u4[0] = *(const u16x4*)(ps + (jn * 16 + l15) * 36 + qd * 8);
            bpu.u4[1] = *(const u16x4*)(ps + (jn * 16 + l15) * 36 + qd * 8 + 4);
            bp[jn] = bpu.h8;
        }

        __builtin_amdgcn_s_setprio(1);
#pragma unroll
        for (int jn = 0; jn < 4; ++jn)
            lsum[jn] = __builtin_amdgcn_mfma_f32_16x16x32_f16(ones, bp[jn], lsum[jn], 0, 0, 0);
#pragma unroll
        for (int ip = 0; ip < 4; ++ip)
#pragma unroll
            for (int jn = 0; jn < 4; ++jn)
                o[ip][jn] = __builtin_amdgcn_mfma_f32_16x16x32_f16(avU[ip], bp[jn], o[ip][jn], 0, 0, 0);
        __builtin_amdgcn_s_setprio(0);
    };

    for (int kt = 0; kt < 16; kt += 2) {
        body(kt,     scA, scB, avA, avB);
        body(kt + 1, scB, scA, avB, avA);
    }

    // ---- cross-wave sum through LDS (aliases P region; P is dead) ----
    float* Oacc = (float*)smem;                  // [64][68] fp32
    float* la = (float*)smem + 4352;             // [64]

    __syncthreads();
    if (wid == 0) {
#pragma unroll
        for (int jn = 0; jn < 4; ++jn) {
            int q = jn * 16 + l15;
#pragma unroll
            for (int ip = 0; ip < 4; ++ip)
                *(floatx4*)(Oacc + q * 68 + ip * 16 + qd * 4) = o[ip][jn];
            if (qd == 0) la[q] = lsum[jn][0];
        }
    }
    for (int w = 1; w < 4; ++w) {
        __syncthreads();
        if (wid == w) {
#pragma unroll
            for (int jn = 0; jn < 4; ++jn) {
                int q = jn * 16 + l15;
#pragma unroll
                for (int ip = 0; ip < 4; ++ip) {
                    float* p = Oacc + q * 68 + ip * 16 + qd * 4;
                    *(floatx4*)p = *(floatx4*)p + o[ip][jn];
                }
                if (qd == 0) la[q] += lsum[jn][0];
            }
        }
    }
    __syncthreads();

    {
        int q = tid >> 2, d0 = (tid & 3) * 16;
        float inv = __builtin_amdgcn_rcpf(la[q]);
        const float* op = Oacc + q * 68 + d0;
        u16x8 pk0, pk1;
#pragma unroll
        for (int r = 0; r < 8; ++r) pk0[r] = f2h(op[r] * inv);
#pragma unroll
        for (int r = 0; r < 8; ++r) pk1[r] = f2h(op[8 + r] * inv);
        u16* dst = attn + (size_t)(b * SEQ + q0 + q) * D_MODEL + h * DH + d0;
        *(u16x8*)dst = pk0;
        *(u16x8*)(dst + 8) = pk1;
    }
}

// ---------------- out GEMM: C[4096][768] = A * WoT^T + bias (fp32 out) ----------------
// 64x64 tile (768 blocks, 3/CU), BK=64, 4 waves each 32x32.

__global__ __launch_bounds__(256) void gemm_out(const u16* __restrict__ A, const u16* __restrict__ Bt,
                                                const float* __restrict__ bias, float* __restrict__ Cout) {
    const int tid = threadIdx.x;
    const int wid = tid >> 6;
    const int lane = tid & 63;
    const int qd = lane >> 4;
    const int l15 = lane & 15;

    const int tn = blockIdx.x * 64;
    const int tm = blockIdx.y * 64;
    const int wm = (wid >> 1) * 32;
    const int wn = (wid & 1) * 32;

    __shared__ alignas(16) u16 As[64 * 64];
    __shared__ alignas(16) u16 Bs[64 * 64];

    floatx4 acc[2][2];
#pragma unroll
    for (int i = 0; i < 2; ++i)
#pragma unroll
        for (int j = 0; j < 2; ++j) acc[i][j] = (floatx4)(0.0f);

    const u16* Ag[2];
    const u16* Bg[2];
#pragma unroll
    for (int rd = 0; rd < 2; ++rd) {
        int s = rd * 256 + tid;
        int r = s >> 3, bl = (s & 7) ^ (r & 7);
        Ag[rd] = A + (size_t)(tm + r) * 768 + bl * 8;
        Bg[rd] = Bt + (size_t)(tn + r) * 768 + bl * 8;
    }

    for (int kb = 0; kb < 768; kb += 64) {
        __syncthreads();
#pragma unroll
        for (int rd = 0; rd < 2; ++rd) {
            gload_lds16(Ag[rd] + kb, As + (size_t)(rd * 256 + tid) * 8);
            gload_lds16(Bg[rd] + kb, Bs + (size_t)(rd * 256 + tid) * 8);
        }
        __syncthreads();

#pragma unroll
        for (int ks = 0; ks < 2; ++ks) {
            halfx8 af[2], bf[2];
#pragma unroll
            for (int i = 0; i < 2; ++i) {
                int r = wm + i * 16 + l15;
                af[i] = *(const halfx8*)(As + r * 64 + (((ks * 4 + qd) ^ (r & 7)) * 8));
                int r2 = wn + i * 16 + l15;
                bf[i] = *(const halfx8*)(Bs + r2 * 64 + (((ks * 4 + qd) ^ (r2 & 7)) * 8));
            }
#pragma unroll
            for (int i = 0; i < 2; ++i)
#pragma unroll
                for (int j = 0; j < 2; ++j)
                    acc[i][j] = __builtin_amdgcn_mfma_f32_16x16x32_f16(af[i], bf[j], acc[i][j], 0, 0, 0);
        }
    }

#pragma unroll
    for (int j = 0; j < 2; ++j) {
        int col = tn + wn + j * 16 + l15;
        float bv = bias[col];
#pragma unroll
        for (int i = 0; i < 2; ++i) {
            int row0 = tm + wm + i * 16 + qd * 4;
#pragma unroll
            for (int r = 0; r < 4; ++r)
                Cout[(size_t)(row0 + r) * 768 + col] = acc[i][j][r] + bv;
        }
    }
}

// ---------------- launch ----------------

extern "C" void kernel_launch(void* const* d_in, const int* in_sizes, int n_in,
                              void* d_out, int out_size, void* d_ws, size_t ws_size,
                              hipStream_t stream) {
    const float* x  = (const float*)d_in[0];
    const float* Wq = (const float*)d_in[1];
    const float* bq = (const float*)d_in[2];
    const float* Wk = (const float*)d_in[3];
    const float* bk = (const float*)d_in[4];
    const float* Wv = (const float*)d_in[5];
    const float* bv = (const float*)d_in[6];
    const float* Wo = (const float*)d_in[7];
    const float* bo = (const float*)d_in[8];

    char* ws = (char*)d_ws;
    size_t off = 0;
    auto take = [&](size_t bytes) -> char* {
        char* p = ws + off;
        off += (bytes + 255) & ~(size_t)255;
        return p;
    };
    u16* WqkvT = (u16*)take((size_t)DQKV * D_MODEL * 2);
    u16* WoT   = (u16*)take((size_t)D_MODEL * D_MODEL * 2);
    u16* qP    = (u16*)take((size_t)MTOK * D_MODEL * 2);
    u16* kP    = (u16*)take((size_t)MTOK * D_MODEL * 2);
    u16* vTb   = (u16*)take((size_t)BATCH * NH * DH * SEQ * 2);
    u16* attn  = (u16*)take((size_t)MTOK * D_MODEL * 2);
    // xh (f16 cast of x) aliases the attn buffer: consumed by gemm_qkv before
    // attn_kernel writes it (stream-ordered).
    u16* xh = attn;

    wprep_kernel<<<576 + (MTOK * D_MODEL / 2048), 256, 0, stream>>>(Wq, Wk, Wv, Wo, x, WqkvT, WoT, xh);
    gemm_qkv<<<dim3(DQKV / 128, MTOK / 64), 256, 0, stream>>>(xh, WqkvT, bq, bk, bv, qP, kP, vTb);
    attn_kernel<<<dim3(BATCH * NH, SEQ / 64), 256, 0, stream>>>(qP, kP, vTb, attn);
    gemm_out<<<dim3(D_MODEL / 64, MTOK / 64), 256, 0, stream>>>(attn, WoT, bo, (float*)d_out);
}

// Round 10
// 170.834 us; speedup vs baseline: 1.2092x; 1.0082x over previous
//
#include <hip/hip_runtime.h>

typedef unsigned short u16;
typedef __fp16 halfx2 __attribute__((ext_vector_type(2)));
typedef __fp16 halfx8 __attribute__((ext_vector_type(8)));
typedef float floatx4 __attribute__((ext_vector_type(4)));
typedef unsigned short u16x4 __attribute__((ext_vector_type(4)));
typedef unsigned short u16x8 __attribute__((ext_vector_type(8)));

#define D_MODEL 768
#define NH 12
#define DH 64
#define SEQ 2048
#define BATCH 2
#define MTOK 4096            // BATCH*SEQ
#define DQKV 2304

__device__ __forceinline__ u16 f2h(float f) {
    __fp16 h = (__fp16)f;
    return __builtin_bit_cast(u16, h);
}

__device__ __forceinline__ void gload_lds16(const void* g, void* l) {
    __builtin_amdgcn_global_load_lds(
        (const __attribute__((address_space(1))) void*)g,
        (__attribute__((address_space(3))) void*)l, 16, 0, 0);
}

// ---------------- prep: W transposes -> f16 [n][k] (576 blocks) + x -> f16 cast (1536 blocks) ----------------
// LDS pad 66 u16 (stride 33 dwords, gcd=1) -> conflict-free transpose reads.

__global__ __launch_bounds__(256) void wprep_kernel(const float* __restrict__ Wq, const float* __restrict__ Wk,
                                                    const float* __restrict__ Wv, const float* __restrict__ Wo,
                                                    const float* __restrict__ x,
                                                    u16* __restrict__ WqkvT, u16* __restrict__ WoT,
                                                    u16* __restrict__ xh) {
    __shared__ u16 t[64][66];
    int bid = blockIdx.x;
    int tid = threadIdx.x;
    if (bid >= 576) {
        // x fp32 -> f16, 2048 elems per block
        int idx = (bid - 576) * 2048 + tid * 8;
        float4 v0 = *(const float4*)(x + idx);
        float4 v1 = *(const float4*)(x + idx + 4);
        union { u16x8 u; halfx2 h[4]; } pk;
        pk.h[0] = __builtin_amdgcn_cvt_pkrtz(v0.x, v0.y);
        pk.h[1] = __builtin_amdgcn_cvt_pkrtz(v0.z, v0.w);
        pk.h[2] = __builtin_amdgcn_cvt_pkrtz(v1.x, v1.y);
        pk.h[3] = __builtin_amdgcn_cvt_pkrtz(v1.z, v1.w);
        *(u16x8*)(xh + idx) = pk.u;
        return;
    }
    int z = bid / 144;
    int t2 = bid % 144;
    int k0 = (t2 / 12) * 64, n0 = (t2 % 12) * 64;
    const float* W = (z == 0) ? Wq : (z == 1) ? Wk : (z == 2) ? Wv : Wo;
    u16* dst = (z < 3) ? (WqkvT + (size_t)z * 768 * 768) : WoT;
#pragma unroll
    for (int p = 0; p < 16; ++p) {
        int idx = p * 256 + tid;
        int kr = idx >> 6, nc = idx & 63;
        t[kr][nc] = f2h(W[(size_t)(k0 + kr) * 768 + n0 + nc]);
    }
    __syncthreads();
#pragma unroll
    for (int p = 0; p < 16; ++p) {
        int idx = p * 256 + tid;
        int nr = idx >> 6, kc = idx & 63;
        dst[(size_t)(n0 + nr) * 768 + k0 + kc] = t[kc][nr];
    }
}

// ---------------- QKV GEMM: 64x128 tile, R21 XCD-chunked swizzle + R20 coalesced epilogue ----------------
// 1D grid 1152 = 18 n x 64 m. swz = (bid&7)*144 + bid>>3 (bijective, 1152%8=0):
// each XCD gets a contiguous 8-m-row x 18-n slab -> A 0.75MB + B 3.4MB ~ one
// 4MB L2 (was: panel-sharing blocks scattered over all 8 XCDs, refetch from L3).

__global__ __launch_bounds__(256) void gemm_qkv(const u16* __restrict__ xh, const u16* __restrict__ Bt,
                                                const float* __restrict__ bq, const float* __restrict__ bk,
                                                const float* __restrict__ bv,
                                                u16* __restrict__ qP, u16* __restrict__ kP,
                                                u16* __restrict__ vTout) {
    const int tid = threadIdx.x;
    const int wid = tid >> 6;
    const int lane = tid & 63;
    const int qd = lane >> 4;
    const int l15 = lane & 15;

    const int bid = blockIdx.x;
    const int swz = (bid & 7) * 144 + (bid >> 3);
    const int tn = (swz % 18) * 128;
    const int tm = (swz / 18) * 64;
    const int wm = (wid >> 1) * 32;
    const int wn = (wid & 1) * 64;

    __shared__ alignas(16) u16 sm[12288];      // As 64x64 (4096) + Bs 128x64 (8192); epilogue reuses as T[64][132]
    u16* As = sm;
    u16* Bs = sm + 4096;

    floatx4 acc[2][4];
#pragma unroll
    for (int i = 0; i < 2; ++i)
#pragma unroll
        for (int j = 0; j < 4; ++j) acc[i][j] = (floatx4)(0.0f);

    const u16* Ag[2];
#pragma unroll
    for (int rd = 0; rd < 2; ++rd) {
        int s = rd * 256 + tid;
        int r = s >> 3, bl = (s & 7) ^ (r & 7);
        Ag[rd] = xh + (size_t)(tm + r) * 768 + bl * 8;
    }
    const u16* Bg[4];
#pragma unroll
    for (int rd = 0; rd < 4; ++rd) {
        int s = rd * 256 + tid;
        int r = s >> 3, bl = (s & 7) ^ (r & 7);
        Bg[rd] = Bt + (size_t)(tn + r) * 768 + bl * 8;
    }

    for (int kb = 0; kb < 768; kb += 64) {
        __syncthreads();
#pragma unroll
        for (int rd = 0; rd < 2; ++rd)
            gload_lds16(Ag[rd] + kb, As + (size_t)(rd * 256 + tid) * 8);
#pragma unroll
        for (int rd = 0; rd < 4; ++rd)
            gload_lds16(Bg[rd] + kb, Bs + (size_t)(rd * 256 + tid) * 8);
        __syncthreads();

#pragma unroll
        for (int ks = 0; ks < 2; ++ks) {
            halfx8 af[2], bf[4];
#pragma unroll
            for (int i = 0; i < 2; ++i) {
                int r = wm + i * 16 + l15;
                af[i] = *(const halfx8*)(As + r * 64 + (((ks * 4 + qd) ^ (r & 7)) * 8));
            }
#pragma unroll
            for (int j = 0; j < 4; ++j) {
                int r2 = wn + j * 16 + l15;
                bf[j] = *(const halfx8*)(Bs + r2 * 64 + (((ks * 4 + qd) ^ (r2 & 7)) * 8));
            }
#pragma unroll
            for (int i = 0; i < 2; ++i)
#pragma unroll
                for (int j = 0; j < 4; ++j)
                    acc[i][j] = __builtin_amdgcn_mfma_f32_16x16x32_f16(af[i], bf[j], acc[i][j], 0, 0, 0);
        }
    }

    const float cscale = 0.125f * 1.44269504088896340736f;
    const int rgn = (tn < 768) ? 0 : (tn < 1536) ? 1 : 2;   // block-uniform (tn step 128; 768/128=6)
    const float* bsrc = (rgn == 0) ? bq : (rgn == 1) ? bk : bv;

    __syncthreads();   // all waves done with As/Bs before T aliases them
    u16* T = sm;       // [64 tokens][132 cols]

#pragma unroll
    for (int j = 0; j < 4; ++j) {
        int col = wn + j * 16 + l15;
        int cl = tn + col - rgn * 768;
        float bvv = bsrc[cl];
#pragma unroll
        for (int i = 0; i < 2; ++i) {
            int row0 = wm + i * 16 + qd * 4;
#pragma unroll
            for (int r = 0; r < 4; ++r) {
                float v = acc[i][j][r] + bvv;
                if (rgn == 0) v *= cscale;
                T[(size_t)(row0 + r) * 132 + col] = f2h(v);
            }
        }
    }
    __syncthreads();

    const int hbase = (tn - rgn * 768) >> 6;   // head index of col 0 (even)
    const int b = tm >> 11, s0 = tm & 2047;    // block-uniform (64-token tile within one batch)

    if (rgn < 2) {
        u16* dst = (rgn == 0) ? qP : kP;
#pragma unroll
        for (int it = 0; it < 4; ++it) {
            int idx = it * 256 + tid;
            int token = idx >> 4, rem = idx & 15;
            int hh = rem >> 3, sub = rem & 7;
            u16x8 v = *(const u16x8*)(T + (size_t)token * 132 + hh * 64 + sub * 8);
            *(u16x8*)(dst + ((size_t)(b * NH + hbase + hh) * SEQ + s0 + token) * DH + sub * 8) = v;
        }
    } else {
#pragma unroll
        for (int it = 0; it < 8; ++it) {
            int idx = it * 256 + tid;
            int c = idx >> 4, tq = (idx & 15) * 4;
            u16x4 v;
#pragma unroll
            for (int k = 0; k < 4; ++k) v[k] = T[(size_t)(tq + k) * 132 + c];
            int h = hbase + (c >> 6), d = c & 63;
            *(u16x4*)(vTout + ((size_t)(b * NH + h) * 64 + d) * SEQ + s0 + tq) = v;
        }
    }
}

// ---------------- attention R13 (verbatim — best measured: 59.2 us) ----------------
// grid = (24 bh fast, 32 q-tiles of 64): 24%8==0 -> all 32 blocks of a bh land
// on the same XCD (K/V 512KB L2-resident) — already ideal T1 locality.
// R12-R19 post-mortems: occupancy 17-32%, K prefetch d1->d2, shared/swizzled P,
// d-split PV all FLAT or worse; ~59-60 us is this decomposition's floor.

__global__ __launch_bounds__(256, 2) void attn_kernel(const u16* __restrict__ qP, const u16* __restrict__ kP,
                                                      const u16* __restrict__ vT, u16* __restrict__ attn) {
    const int tid = threadIdx.x;
    const int wid = tid >> 6;
    const int lane = tid & 63;
    const int qd = lane >> 4;
    const int l15 = lane & 15;

    const int bh = blockIdx.x;
    const int b = bh / NH, h = bh % NH;
    const int q0 = blockIdx.y * 64;

    __shared__ alignas(16) u16 smem[9216];   // 18 KB: per wave [64][36] P
    u16* ps = smem + wid * 2304;

    halfx8 aq[4][2];
#pragma unroll
    for (int jn = 0; jn < 4; ++jn)
#pragma unroll
        for (int ks = 0; ks < 2; ++ks)
            aq[jn][ks] = *(const halfx8*)(qP + (size_t)(bh * SEQ + q0 + jn * 16 + l15) * DH + ks * 32 + qd * 8);

    halfx8 ones;
#pragma unroll
    for (int j = 0; j < 8; ++j) ones[j] = (__fp16)1.0f;

    floatx4 o[4][4];
#pragma unroll
    for (int ip = 0; ip < 4; ++ip)
#pragma unroll
        for (int jn = 0; jn < 4; ++jn) o[ip][jn] = (floatx4)(0.0f);
    floatx4 lsum[4];
#pragma unroll
    for (int jn = 0; jn < 4; ++jn) lsum[jn] = (floatx4)(0.0f);

    const u16* kbase = kP + (size_t)(bh * SEQ + wid * 32 + l15) * DH + qd * 8;
    const u16* vbase = vT + (size_t)(bh * 64 + l15) * SEQ + wid * 32 + qd * 8;

    // prologue: load K(0), V(0); sc(0) = QK(0)
    halfx8 avA[4], avB[4];
    floatx4 scA[2][4], scB[2][4];
    {
        halfx8 akp[2][2];
#pragma unroll
        for (int mi = 0; mi < 2; ++mi)
#pragma unroll
            for (int ks = 0; ks < 2; ++ks)
                akp[mi][ks] = *(const halfx8*)(kbase + (size_t)(mi * 16) * DH + ks * 32);
#pragma unroll
        for (int ip = 0; ip < 4; ++ip)
            avA[ip] = *(const halfx8*)(vbase + (size_t)(ip * 16) * SEQ);

#pragma unroll
        for (int mi = 0; mi < 2; ++mi)
#pragma unroll
            for (int jn = 0; jn < 4; ++jn) scA[mi][jn] = (floatx4)(0.0f);
#pragma unroll
        for (int ks = 0; ks < 2; ++ks)
#pragma unroll
            for (int mi = 0; mi < 2; ++mi)
#pragma unroll
                for (int jn = 0; jn < 4; ++jn)
                    scA[mi][jn] = __builtin_amdgcn_mfma_f32_16x16x32_f16(akp[mi][ks], aq[jn][ks], scA[mi][jn], 0, 0, 0);
    }

    // body(t): issue K(t+1), V(t+1)->avF; exp(sc(t)=scC); QK(t+1)->scN; PV(t) with avU
    auto body = [&](int kt,
                    floatx4 (&scC)[2][4], floatx4 (&scN)[2][4],
                    halfx8 (&avU)[4], halfx8 (&avF)[4]) {
        const int kt1 = (kt + 1) & 15;   // wrap harmless (valid addresses, values unused)

        halfx8 akn[2][2];
#pragma unroll
        for (int mi = 0; mi < 2; ++mi)
#pragma unroll
            for (int ks = 0; ks < 2; ++ks)
                akn[mi][ks] = *(const halfx8*)(kbase + (size_t)(kt1 * 128 + mi * 16) * DH + ks * 32);
#pragma unroll
        for (int ip = 0; ip < 4; ++ip)
            avF[ip] = *(const halfx8*)(vbase + (size_t)(ip * 16) * SEQ + kt1 * 128);

        // exp(t) from scC (computed last iteration -> no MFMA hazard)
#pragma unroll
        for (int mi = 0; mi < 2; ++mi)
#pragma unroll
            for (int jn = 0; jn < 4; ++jn) {
                float p0 = __builtin_amdgcn_exp2f(scC[mi][jn][0]);
                float p1 = __builtin_amdgcn_exp2f(scC[mi][jn][1]);
                float p2 = __builtin_amdgcn_exp2f(scC[mi][jn][2]);
                float p3 = __builtin_amdgcn_exp2f(scC[mi][jn][3]);
                union { u16x4 u; halfx2 h[2]; } pk;
                pk.h[0] = __builtin_amdgcn_cvt_pkrtz(p0, p1);
                pk.h[1] = __builtin_amdgcn_cvt_pkrtz(p2, p3);
                *(u16x4*)(ps + (jn * 16 + l15) * 36 + mi * 16 + qd * 4) = pk.u;
            }

        // QK(t+1) on the MFMA pipe (overlaps the exp/pack VALU of other waves)
#pragma unroll
        for (int mi = 0; mi < 2; ++mi)
#pragma unroll
            for (int jn = 0; jn < 4; ++jn) scN[mi][jn] = (floatx4)(0.0f);
        __builtin_amdgcn_s_setprio(1);
#pragma unroll
        for (int ks = 0; ks < 2; ++ks)
#pragma unroll
            for (int mi = 0; mi < 2; ++mi)
#pragma unroll
                for (int jn = 0; jn < 4; ++jn)
                    scN[mi][jn] = __builtin_amdgcn_mfma_f32_16x16x32_f16(akn[mi][ks], aq[jn][ks], scN[mi][jn], 0, 0, 0);
        __builtin_amdgcn_s_setprio(0);

        // P(t) fragments (same-wave DS write->read ordering)
        halfx8 bp[4];
#pragma unroll
        for (int jn = 0; jn < 4; ++jn) {
            union { halfx8 h8; u16x4 u4[2]; } bpu;
            bpu.u4[0] = *(const u16x4*)(ps + (jn * 16 + l15) * 36 + qd * 8);
            bpu.u4[1] = *(const u16x4*)(ps + (jn * 16 + l15) * 36 + qd * 8 + 4);
            bp[jn] = bpu.h8;
        }

        __builtin_amdgcn_s_setprio(1);
#pragma unroll
        for (int jn = 0; jn < 4; ++jn)
            lsum[jn] = __builtin_amdgcn_mfma_f32_16x16x32_f16(ones, bp[jn], lsum[jn], 0, 0, 0);
#pragma unroll
        for (int ip = 0; ip < 4; ++ip)
#pragma unroll
            for (int jn = 0; jn < 4; ++jn)
                o[ip][jn] = __builtin_amdgcn_mfma_f32_16x16x32_f16(avU[ip], bp[jn], o[ip][jn], 0, 0, 0);
        __builtin_amdgcn_s_setprio(0);
    };

    for (int kt = 0; kt < 16; kt += 2) {
        body(kt,     scA, scB, avA, avB);
        body(kt + 1, scB, scA, avB, avA);
    }

    // ---- cross-wave sum through LDS (aliases P region; P is dead) ----
    float* Oacc = (float*)smem;                  // [64][68] fp32
    float* la = (float*)smem + 4352;             // [64]

    __syncthreads();
    if (wid == 0) {
#pragma unroll
        for (int jn = 0; jn < 4; ++jn) {
            int q = jn * 16 + l15;
#pragma unroll
            for (int ip = 0; ip < 4; ++ip)
                *(floatx4*)(Oacc + q * 68 + ip * 16 + qd * 4) = o[ip][jn];
            if (qd == 0) la[q] = lsum[jn][0];
        }
    }
    for (int w = 1; w < 4; ++w) {
        __syncthreads();
        if (wid == w) {
#pragma unroll
            for (int jn = 0; jn < 4; ++jn) {
                int q = jn * 16 + l15;
#pragma unroll
                for (int ip = 0; ip < 4; ++ip) {
                    float* p = Oacc + q * 68 + ip * 16 + qd * 4;
                    *(floatx4*)p = *(floatx4*)p + o[ip][jn];
                }
                if (qd == 0) la[q] += lsum[jn][0];
            }
        }
    }
    __syncthreads();

    {
        int q = tid >> 2, d0 = (tid & 3) * 16;
        float inv = __builtin_amdgcn_rcpf(la[q]);
        const float* op = Oacc + q * 68 + d0;
        u16x8 pk0, pk1;
#pragma unroll
        for (int r = 0; r < 8; ++r) pk0[r] = f2h(op[r] * inv);
#pragma unroll
        for (int r = 0; r < 8; ++r) pk1[r] = f2h(op[8 + r] * inv);
        u16* dst = attn + (size_t)(b * SEQ + q0 + q) * D_MODEL + h * DH + d0;
        *(u16x8*)dst = pk0;
        *(u16x8*)(dst + 8) = pk1;
    }
}

// ---------------- out GEMM: C[4096][768] = A * WoT^T + bias (fp32 out) ----------------
// R21: 1D grid 768 = 12 n x 64 m, XCD-chunked swizzle (chunk 96 -> A 0.75MB +
// B 1.1MB per-XCD slab, L2-resident). Epilogue stages the 64x64 fp32 tile in
// LDS ([64][66], 2-way-free banks) and writes float4 rows (256B coalesced)
// instead of 16 scalar stores/lane.

__global__ __launch_bounds__(256) void gemm_out(const u16* __restrict__ A, const u16* __restrict__ Bt,
                                                const float* __restrict__ bias, float* __restrict__ Cout) {
    const int tid = threadIdx.x;
    const int wid = tid >> 6;
    const int lane = tid & 63;
    const int qd = lane >> 4;
    const int l15 = lane & 15;

    const int bid = blockIdx.x;
    const int swz = (bid & 7) * 96 + (bid >> 3);
    const int tn = (swz % 12) * 64;
    const int tm = (swz / 12) * 64;
    const int wm = (wid >> 1) * 32;
    const int wn = (wid & 1) * 32;

    __shared__ alignas(16) u16 sm[8704];   // As 4096 + Bs 4096 u16; epilogue T[64][66] fp32 (16.9KB)
    u16* As = sm;
    u16* Bs = sm + 4096;

    floatx4 acc[2][2];
#pragma unroll
    for (int i = 0; i < 2; ++i)
#pragma unroll
        for (int j = 0; j < 2; ++j) acc[i][j] = (floatx4)(0.0f);

    const u16* Ag[2];
    const u16* Bg[2];
#pragma unroll
    for (int rd = 0; rd < 2; ++rd) {
        int s = rd * 256 + tid;
        int r = s >> 3, bl = (s & 7) ^ (r & 7);
        Ag[rd] = A + (size_t)(tm + r) * 768 + bl * 8;
        Bg[rd] = Bt + (size_t)(tn + r) * 768 + bl * 8;
    }

    for (int kb = 0; kb < 768; kb += 64) {
        __syncthreads();
#pragma unroll
        for (int rd = 0; rd < 2; ++rd) {
            gload_lds16(Ag[rd] + kb, As + (size_t)(rd * 256 + tid) * 8);
            gload_lds16(Bg[rd] + kb, Bs + (size_t)(rd * 256 + tid) * 8);
        }
        __syncthreads();

#pragma unroll
        for (int ks = 0; ks < 2; ++ks) {
            halfx8 af[2], bf[2];
#pragma unroll
            for (int i = 0; i < 2; ++i) {
                int r = wm + i * 16 + l15;
                af[i] = *(const halfx8*)(As + r * 64 + (((ks * 4 + qd) ^ (r & 7)) * 8));
                int r2 = wn + i * 16 + l15;
                bf[i] = *(const halfx8*)(Bs + r2 * 64 + (((ks * 4 + qd) ^ (r2 & 7)) * 8));
            }
#pragma unroll
            for (int i = 0; i < 2; ++i)
#pragma unroll
                for (int j = 0; j < 2; ++j)
                    acc[i][j] = __builtin_amdgcn_mfma_f32_16x16x32_f16(af[i], bf[j], acc[i][j], 0, 0, 0);
        }
    }

    __syncthreads();                 // done with As/Bs
    float* T = (float*)sm;           // [64][66] fp32

#pragma unroll
    for (int j = 0; j < 2; ++j) {
        int col = wn + j * 16 + l15;
        float bv = bias[tn + col];
#pragma unroll
        for (int i = 0; i < 2; ++i) {
            int row0 = wm + i * 16 + qd * 4;
#pragma unroll
            for (int r = 0; r < 4; ++r)
                T[(size_t)(row0 + r) * 66 + col] = acc[i][j][r] + bv;
        }
    }
    __syncthreads();

    // coalesced float4 writeback: 64 rows x 16 quads, 4 iterations of 256 lanes
#pragma unroll
    for (int it = 0; it < 4; ++it) {
        int idx = it * 256 + tid;
        int row = idx >> 4, c4 = (idx & 15) * 4;
        floatx4 v = *(const floatx4*)(T + (size_t)row * 66 + c4);
        *(floatx4*)(Cout + (size_t)(tm + row) * 768 + tn + c4) = v;
    }
}

// ---------------- launch ----------------

extern "C" void kernel_launch(void* const* d_in, const int* in_sizes, int n_in,
                              void* d_out, int out_size, void* d_ws, size_t ws_size,
                              hipStream_t stream) {
    const float* x  = (const float*)d_in[0];
    const float* Wq = (const float*)d_in[1];
    const float* bq = (const float*)d_in[2];
    const float* Wk = (const float*)d_in[3];
    const float* bk = (const float*)d_in[4];
    const float* Wv = (const float*)d_in[5];
    const float* bv = (const float*)d_in[6];
    const float* Wo = (const float*)d_in[7];
    const float* bo = (const float*)d_in[8];

    char* ws = (char*)d_ws;
    size_t off = 0;
    auto take = [&](size_t bytes) -> char* {
        char* p = ws + off;
        off += (bytes + 255) & ~(size_t)255;
        return p;
    };
    u16* WqkvT = (u16*)take((size_t)DQKV * D_MODEL * 2);
    u16* WoT   = (u16*)take((size_t)D_MODEL * D_MODEL * 2);
    u16* qP    = (u16*)take((size_t)MTOK * D_MODEL * 2);
    u16* kP    = (u16*)take((size_t)MTOK * D_MODEL * 2);
    u16* vTb   = (u16*)take((size_t)BATCH * NH * DH * SEQ * 2);
    u16* attn  = (u16*)take((size_t)MTOK * D_MODEL * 2);
    // xh (f16 cast of x) aliases the attn buffer: consumed by gemm_qkv before
    // attn_kernel writes it (stream-ordered).
    u16* xh = attn;

    wprep_kernel<<<576 + (MTOK * D_MODEL / 2048), 256, 0, stream>>>(Wq, Wk, Wv, Wo, x, WqkvT, WoT, xh);
    gemm_qkv<<<1152, 256, 0, stream>>>(xh, WqkvT, bq, bk, bv, qP, kP, vTb);
    attn_kernel<<<dim3(BATCH * NH, SEQ / 64), 256, 0, stream>>>(qP, kP, vTb, attn);
    gemm_out<<<768, 256, 0, stream>>>(attn, WoT, bo, (float*)d_out);
}